// Round 1
// baseline (385.847 us; speedup 1.0000x reference)
//
#include <hip/hip_runtime.h>
#include <cmath>

// ---------------------------------------------------------------------------
// PatchTST encoder layer w/ p-RoPE, MI355X (gfx950).
// bf16 MFMA (16x16x32) for all GEMMs + flash attention; fp32 residual path.
// Verified fragment layouts (guide §3, m89/m120):
//   A-frag: A[m=lane&15][k=(lane>>4)*8+j]   (8 contiguous bf16 -> ds_read_b128)
//   B-frag: B[k=(lane>>4)*8+j][n=lane&15]   (same pattern on B^T rows)
//   C/D   : col=lane&15, row=(lane>>4)*4+reg
// LDS tiles use XOR swizzle (8-elem chunks) -> balanced banks, no padding.
// ---------------------------------------------------------------------------

typedef __bf16 bf16_t;
typedef bf16_t bf16x8 __attribute__((ext_vector_type(8)));
typedef float floatx4 __attribute__((ext_vector_type(4)));

#define MFMA(a, b, c) __builtin_amdgcn_mfma_f32_16x16x32_bf16((a), (b), (c), 0, 0, 0)

__device__ __forceinline__ bf16_t f2bf(float f) { return (bf16_t)f; }

// ---------------------------------------------------------------------------
// Weight transpose + cast: in [R][C] fp32 -> out [C][R] bf16
// ---------------------------------------------------------------------------
__global__ __launch_bounds__(256) void k_transpose_cast(
    const float* __restrict__ in, bf16_t* __restrict__ out, int R, int C) {
  __shared__ float tile[32][33];
  const int c0 = blockIdx.x * 32, r0 = blockIdx.y * 32;
  const int tx = threadIdx.x & 31, ty = threadIdx.x >> 5;  // 32 x 8
#pragma unroll
  for (int p = 0; p < 4; p++) {
    int r = ty + p * 8;
    tile[r][tx] = in[(size_t)(r0 + r) * C + c0 + tx];
  }
  __syncthreads();
#pragma unroll
  for (int p = 0; p < 4; p++) {
    int r = ty + p * 8;
    out[(size_t)(c0 + r) * R + r0 + tx] = f2bf(tile[tx][r]);
  }
}

// ---------------------------------------------------------------------------
// LayerNorm over 768 cols, fp32 in -> bf16 out. One block (256 thr) per row.
// ---------------------------------------------------------------------------
__global__ __launch_bounds__(256) void k_layernorm(
    const float* __restrict__ x, const float* __restrict__ g,
    const float* __restrict__ b, bf16_t* __restrict__ out) {
  const int row = blockIdx.x;
  const float* xr = x + (size_t)row * 768;
  const int t = threadIdx.x;
  float v0 = xr[t], v1 = xr[t + 256], v2 = xr[t + 512];
  float s = v0 + v1 + v2;
  float s2 = v0 * v0 + v1 * v1 + v2 * v2;
#pragma unroll
  for (int off = 32; off; off >>= 1) {
    s += __shfl_xor(s, off);
    s2 += __shfl_xor(s2, off);
  }
  __shared__ float ra[4], rb[4];
  const int w = t >> 6;
  if ((t & 63) == 0) { ra[w] = s; rb[w] = s2; }
  __syncthreads();
  s = ra[0] + ra[1] + ra[2] + ra[3];
  s2 = rb[0] + rb[1] + rb[2] + rb[3];
  const float mu = s * (1.0f / 768.0f);
  const float var = s2 * (1.0f / 768.0f) - mu * mu;
  const float rstd = rsqrtf(var + 1e-5f);
  bf16_t* orow = out + (size_t)row * 768;
  orow[t]       = f2bf((v0 - mu) * rstd * g[t]       + b[t]);
  orow[t + 256] = f2bf((v1 - mu) * rstd * g[t + 256] + b[t + 256]);
  orow[t + 512] = f2bf((v2 - mu) * rstd * g[t + 512] + b[t + 512]);
}

// ---------------------------------------------------------------------------
// Generic bf16 MFMA GEMM:  C[M,N] = A[M,K] @ Bt[N,K]^T  with mode epilogues.
// 128x128 tile / block (4 waves, each 64x64 = 4x4 mfma tiles), BK=64.
// mode 0: QKV   -> bias, (q: *0.125), p-RoPE on q,k; q,k -> [bh][t][64] bf16,
//                  v -> [bh][64][2048] bf16 (transposed for flash staging)
// mode 1: WO    -> fp32 out = acc + bias + resid
// mode 2: FFN1  -> bf16 out = gelu_exact(acc + bias)
// mode 3: FFN2  -> fp32 out = acc + bias + resid   (writes d_out)
// ---------------------------------------------------------------------------
struct GemmP {
  const bf16_t* A;
  const bf16_t* Bt;
  int M, N, K, mode;
  const float* bias0;
  const float* bias1;
  const float* bias2;
  const float* resid;
  float* outF;
  bf16_t* outB0;
  bf16_t* outB1;
  bf16_t* outB2;
};

__global__ __launch_bounds__(256) void k_gemm(GemmP p) {
  __shared__ bf16_t lA[128 * 64];
  __shared__ bf16_t lB[128 * 64];
  const int tid = threadIdx.x;
  const int lane = tid & 63, wave = tid >> 6;
  const int quad = lane >> 4, l15 = lane & 15;
  const int wm = (wave >> 1) * 64, wn = (wave & 1) * 64;
  const int m0 = blockIdx.y * 128, n0 = blockIdx.x * 128;

  const floatx4 z4 = {0.f, 0.f, 0.f, 0.f};
  floatx4 acc[4][4];
#pragma unroll
  for (int i = 0; i < 4; i++)
#pragma unroll
    for (int j = 0; j < 4; j++) acc[i][j] = z4;

  for (int k0 = 0; k0 < p.K; k0 += 64) {
#pragma unroll
    for (int pp = 0; pp < 4; pp++) {
      int idx = pp * 256 + tid;
      int r = idx >> 3, c8 = (idx & 7) << 3;
      int sw = c8 ^ ((r & 7) << 3);
      *(bf16x8*)&lA[r * 64 + sw] =
          *(const bf16x8*)(p.A + (size_t)(m0 + r) * p.K + k0 + c8);
      *(bf16x8*)&lB[r * 64 + sw] =
          *(const bf16x8*)(p.Bt + (size_t)(n0 + r) * p.K + k0 + c8);
    }
    __syncthreads();
#pragma unroll
    for (int ks = 0; ks < 2; ks++) {
      const int c = ks * 32 + quad * 8;
      bf16x8 af[4], bfr[4];
#pragma unroll
      for (int i = 0; i < 4; i++) {
        int ra = wm + i * 16 + l15;
        af[i] = *(const bf16x8*)&lA[ra * 64 + (c ^ ((ra & 7) << 3))];
        int rb = wn + i * 16 + l15;
        bfr[i] = *(const bf16x8*)&lB[rb * 64 + (c ^ ((rb & 7) << 3))];
      }
#pragma unroll
      for (int i = 0; i < 4; i++)
#pragma unroll
        for (int j = 0; j < 4; j++) acc[i][j] = MFMA(af[i], bfr[j], acc[i][j]);
    }
    __syncthreads();
  }

  // ---- epilogues ----
  if (p.mode == 0) {
    const int gnw = n0 + wn;            // 64-aligned col window (one head)
    const int region = gnw / 768;       // 0=q 1=k 2=v
    const int rem = gnw - region * 768;
    const int h = rem >> 6;
    const float* bias = (region == 0) ? p.bias0 : (region == 1 ? p.bias1 : p.bias2);
    float bb[4];
#pragma unroll
    for (int j = 0; j < 4; j++) bb[j] = bias[h * 64 + j * 16 + l15];
    if (region < 2) {
      bf16_t* outp = (region == 0) ? p.outB0 : p.outB1;
      const float scale = (region == 0) ? 0.125f : 1.0f;
      // timescale: 10000^(d/32) for d=lane&15 (rope_angles=16)
      const float inv_ts = exp2f(-(float)l15 * (13.287712379549449f / 32.0f));
#pragma unroll
      for (int i = 0; i < 4; i++) {
#pragma unroll
        for (int reg = 0; reg < 4; reg++) {
          int row = m0 + wm + i * 16 + quad * 4 + reg;
          int b = row >> 11, t = row & 2047;
          float sn, cs;
          sincosf((float)t * inv_ts, &sn, &cs);
          float v0 = (acc[i][0][reg] + bb[0]) * scale;
          float v1 = (acc[i][1][reg] + bb[1]) * scale;
          float v2 = (acc[i][2][reg] + bb[2]) * scale;
          float v3 = (acc[i][3][reg] + bb[3]) * scale;
          bf16_t* op = outp + (((size_t)(b * 12 + h) * 2048 + t) << 6);
          op[l15]      = f2bf(v0 * cs - v2 * sn);
          op[16 + l15] = f2bf(v1);
          op[32 + l15] = f2bf(v2 * cs + v0 * sn);
          op[48 + l15] = f2bf(v3);
        }
      }
    } else {
#pragma unroll
      for (int i = 0; i < 4; i++)
#pragma unroll
        for (int j = 0; j < 4; j++)
#pragma unroll
          for (int reg = 0; reg < 4; reg++) {
            int row = m0 + wm + i * 16 + quad * 4 + reg;
            int b = row >> 11, t = row & 2047;
            int d = j * 16 + l15;
            p.outB2[(((size_t)(b * 12 + h) * 64 + d) << 11) + t] =
                f2bf(acc[i][j][reg] + bb[j]);
          }
    }
  } else if (p.mode == 2) {
#pragma unroll
    for (int i = 0; i < 4; i++)
#pragma unroll
      for (int j = 0; j < 4; j++)
#pragma unroll
        for (int reg = 0; reg < 4; reg++) {
          int row = m0 + wm + i * 16 + quad * 4 + reg;
          int col = n0 + wn + j * 16 + l15;
          float x = acc[i][j][reg] + p.bias0[col];
          float gv = 0.5f * x * (1.0f + erff(x * 0.70710678118654752f));
          p.outB0[(size_t)row * p.N + col] = f2bf(gv);
        }
  } else {  // mode 1 / 3: fp32 out + residual
#pragma unroll
    for (int i = 0; i < 4; i++)
#pragma unroll
      for (int j = 0; j < 4; j++)
#pragma unroll
        for (int reg = 0; reg < 4; reg++) {
          int row = m0 + wm + i * 16 + quad * 4 + reg;
          int col = n0 + wn + j * 16 + l15;
          p.outF[(size_t)row * p.N + col] =
              acc[i][j][reg] + p.bias0[col] + p.resid[(size_t)row * p.N + col];
        }
  }
}

// ---------------------------------------------------------------------------
// Flash attention. Grid (32 q-tiles of 64 rows, 24 b*h). 4 waves x 16 q-rows.
// LDS: lK [128][64] (union with per-wave P [16][128]) + lV [64][128], all
// XOR-swizzled in 8-elem chunks. Online softmax in fp32.
// Variate bias is uniform per kv tile (tile size 128 == S).
// ---------------------------------------------------------------------------
__global__ __launch_bounds__(256) void k_flash(
    const bf16_t* __restrict__ qh, const bf16_t* __restrict__ kh,
    const bf16_t* __restrict__ vt, const float* __restrict__ ab,
    bf16_t* __restrict__ attnA) {
  __shared__ bf16_t sm[16384];  // 32 KiB
  bf16_t* lK = sm;              // [128][64] swizzled  (8192)
  bf16_t* lP = sm;              // union: 4 waves x [16][128] swizzled
  bf16_t* lV = sm + 8192;       // [64][128] swizzled  (8192)

  const int tid = threadIdx.x, lane = tid & 63, wave = tid >> 6;
  const int quad = lane >> 4, l15 = lane & 15;
  const int qtile = blockIdx.x, bh = blockIdx.y;
  const int h = bh % 12, bq = bh / 12;
  const int qr0 = qtile * 64 + wave * 16;

  const bf16_t* Qb = qh + ((size_t)bh * 2048) * 64;
  const bf16_t* Kb = kh + ((size_t)bh * 2048) * 64;
  const bf16_t* Vb = vt + ((size_t)bh * 64) * 2048;

  bf16x8 qf[2];
#pragma unroll
  for (int ks = 0; ks < 2; ks++)
    qf[ks] = *(const bf16x8*)(Qb + (size_t)(qr0 + l15) * 64 + ks * 32 + quad * 8);

  const floatx4 z4 = {0.f, 0.f, 0.f, 0.f};
  float m_run[4] = {-1e30f, -1e30f, -1e30f, -1e30f};
  float l_run[4] = {0.f, 0.f, 0.f, 0.f};
  floatx4 oacc[4];
#pragma unroll
  for (int dt = 0; dt < 4; dt++) oacc[dt] = z4;

  const float b0 = ab[h * 2], b1 = ab[h * 2 + 1];
  const int myvar = qtile >> 1;

  for (int kv = 0; kv < 16; kv++) {
    const bf16_t* Kg = Kb + kv * (128 * 64);
    const bf16_t* Vg = Vb + kv * 128;
#pragma unroll
    for (int pp = 0; pp < 4; pp++) {
      int idx = pp * 256 + tid;
      int r = idx >> 3, c8 = (idx & 7) << 3;
      *(bf16x8*)&lK[r * 64 + (c8 ^ ((r & 7) << 3))] =
          *(const bf16x8*)(Kg + r * 64 + c8);
      int d = idx >> 4, s8 = (idx & 15) << 3;
      *(bf16x8*)&lV[d * 128 + (s8 ^ ((d & 7) << 3))] =
          *(const bf16x8*)(Vg + (size_t)d * 2048 + s8);
    }
    __syncthreads();

    // S = Q K^T  (8 col-tiles x 2 k-steps)
    floatx4 sacc[8];
#pragma unroll
    for (int ct = 0; ct < 8; ct++) sacc[ct] = z4;
#pragma unroll
    for (int ks = 0; ks < 2; ks++) {
      const int c = ks * 32 + quad * 8;
#pragma unroll
      for (int ct = 0; ct < 8; ct++) {
        int sr = ct * 16 + l15;
        bf16x8 kf = *(const bf16x8*)&lK[sr * 64 + (c ^ ((sr & 7) << 3))];
        sacc[ct] = MFMA(qf[ks], kf, sacc[ct]);
      }
    }

    // online softmax (rows = quad*4+reg, cols across 16 lanes x 8 tiles)
    const float bias = (kv == myvar) ? b0 : b1;
    float mnew[4], alpha[4], rs[4];
#pragma unroll
    for (int reg = 0; reg < 4; reg++) {
      float mx = sacc[0][reg];
#pragma unroll
      for (int ct = 1; ct < 8; ct++) mx = fmaxf(mx, sacc[ct][reg]);
      mx = fmaxf(mx, __shfl_xor(mx, 1));
      mx = fmaxf(mx, __shfl_xor(mx, 2));
      mx = fmaxf(mx, __shfl_xor(mx, 4));
      mx = fmaxf(mx, __shfl_xor(mx, 8));
      mnew[reg] = fmaxf(m_run[reg], mx + bias);
      alpha[reg] = __expf(m_run[reg] - mnew[reg]);
      rs[reg] = 0.f;
    }
#pragma unroll
    for (int ct = 0; ct < 8; ct++)
#pragma unroll
      for (int reg = 0; reg < 4; reg++) {
        float pv = __expf(sacc[ct][reg] + bias - mnew[reg]);
        sacc[ct][reg] = pv;
        rs[reg] += pv;
      }
#pragma unroll
    for (int reg = 0; reg < 4; reg++) {
      rs[reg] += __shfl_xor(rs[reg], 1);
      rs[reg] += __shfl_xor(rs[reg], 2);
      rs[reg] += __shfl_xor(rs[reg], 4);
      rs[reg] += __shfl_xor(rs[reg], 8);
      l_run[reg] = l_run[reg] * alpha[reg] + rs[reg];
      m_run[reg] = mnew[reg];
    }
#pragma unroll
    for (int dt = 0; dt < 4; dt++)
#pragma unroll
      for (int reg = 0; reg < 4; reg++) oacc[dt][reg] *= alpha[reg];

    __syncthreads();  // all waves done reading lK -> safe to overwrite with P

    bf16_t* myP = lP + wave * 2048;
#pragma unroll
    for (int ct = 0; ct < 8; ct++)
#pragma unroll
      for (int reg = 0; reg < 4; reg++) {
        int r = quad * 4 + reg;
        int s = ct * 16 + l15;
        myP[r * 128 + (s ^ ((r & 7) << 3))] = f2bf(sacc[ct][reg]);
      }
    __syncthreads();  // P visible

    // O += P V  (4 k-steps over s, 4 d-tiles)
#pragma unroll
    for (int ks = 0; ks < 4; ks++) {
      const int c = ks * 32 + quad * 8;
      bf16x8 pf = *(const bf16x8*)&myP[l15 * 128 + (c ^ ((l15 & 7) << 3))];
#pragma unroll
      for (int dt = 0; dt < 4; dt++) {
        int dr = dt * 16 + l15;
        bf16x8 vf = *(const bf16x8*)&lV[dr * 128 + (c ^ ((dr & 7) << 3))];
        oacc[dt] = MFMA(pf, vf, oacc[dt]);
      }
    }
    __syncthreads();  // done with lV/lP -> safe to restage
  }

#pragma unroll
  for (int dt = 0; dt < 4; dt++)
#pragma unroll
    for (int reg = 0; reg < 4; reg++) {
      int t = qr0 + quad * 4 + reg;
      float v = oacc[dt][reg] / l_run[reg];
      attnA[((size_t)(bq * 2048 + t)) * 768 + h * 64 + dt * 16 + l15] = f2bf(v);
    }
}

// ---------------------------------------------------------------------------
extern "C" void kernel_launch(void* const* d_in, const int* in_sizes, int n_in,
                              void* d_out, int out_size, void* d_ws,
                              size_t ws_size, hipStream_t stream) {
  const float* hs  = (const float*)d_in[0];
  const float* wq  = (const float*)d_in[1];
  const float* bq  = (const float*)d_in[2];
  const float* wk  = (const float*)d_in[3];
  const float* bk  = (const float*)d_in[4];
  const float* wv  = (const float*)d_in[5];
  const float* bv  = (const float*)d_in[6];
  const float* wo  = (const float*)d_in[7];
  const float* bo  = (const float*)d_in[8];
  const float* ab  = (const float*)d_in[9];
  const float* g1  = (const float*)d_in[10];
  const float* be1 = (const float*)d_in[11];
  const float* g3  = (const float*)d_in[12];
  const float* be3 = (const float*)d_in[13];
  const float* w1  = (const float*)d_in[14];
  const float* b1  = (const float*)d_in[15];
  const float* w2  = (const float*)d_in[16];
  const float* b2  = (const float*)d_in[17];

  char* ws = (char*)d_ws;
  size_t off = 0;
  auto alloc = [&](size_t bytes) -> void* {
    void* p = ws + off;
    off += (bytes + 255) & ~(size_t)255;
    return p;
  };
  bf16_t* wqkvT = (bf16_t*)alloc((size_t)2304 * 768 * 2);
  bf16_t* woT   = (bf16_t*)alloc((size_t)768 * 768 * 2);
  bf16_t* w1T   = (bf16_t*)alloc((size_t)3072 * 768 * 2);
  bf16_t* w2T   = (bf16_t*)alloc((size_t)768 * 3072 * 2);
  bf16_t* ni    = (bf16_t*)alloc((size_t)4096 * 768 * 2);  // reused as ln3 out
  bf16_t* qhB   = (bf16_t*)alloc((size_t)24 * 2048 * 64 * 2);
  bf16_t* khB   = (bf16_t*)alloc((size_t)24 * 2048 * 64 * 2);
  bf16_t* vtB   = (bf16_t*)alloc((size_t)24 * 64 * 2048 * 2);
  bf16_t* attnA = (bf16_t*)alloc((size_t)4096 * 768 * 2);
  float*  resid1 = (float*)alloc((size_t)4096 * 768 * 4);
  bf16_t* ffn1o = qhB;  // overlay: qh..attnA (25.17 MB) dead by FFN1 time

  // weights -> bf16 [N][K]
  k_transpose_cast<<<dim3(24, 24), 256, 0, stream>>>(wq, wqkvT, 768, 768);
  k_transpose_cast<<<dim3(24, 24), 256, 0, stream>>>(wk, wqkvT + 768 * 768, 768, 768);
  k_transpose_cast<<<dim3(24, 24), 256, 0, stream>>>(wv, wqkvT + 2 * 768 * 768, 768, 768);
  k_transpose_cast<<<dim3(24, 24), 256, 0, stream>>>(wo, woT, 768, 768);
  k_transpose_cast<<<dim3(96, 24), 256, 0, stream>>>(w1, w1T, 768, 3072);
  k_transpose_cast<<<dim3(24, 96), 256, 0, stream>>>(w2, w2T, 3072, 768);

  // LN1
  k_layernorm<<<4096, 256, 0, stream>>>(hs, g1, be1, ni);

  // QKV (fused, N=2304) with bias/scale/rope/head-layout epilogue
  GemmP gqkv = {ni, wqkvT, 4096, 2304, 768, 0,
                bq, bk, bv, nullptr, nullptr, qhB, khB, vtB};
  k_gemm<<<dim3(18, 32), 256, 0, stream>>>(gqkv);

  // flash attention
  k_flash<<<dim3(32, 24), 256, 0, stream>>>(qhB, khB, vtB, ab, attnA);

  // attn @ wo + bo + residual(hidden)
  GemmP gwo = {attnA, woT, 4096, 768, 768, 1,
               bo, nullptr, nullptr, hs, resid1, nullptr, nullptr, nullptr};
  k_gemm<<<dim3(6, 32), 256, 0, stream>>>(gwo);

  // LN3
  k_layernorm<<<4096, 256, 0, stream>>>(resid1, g3, be3, ni);

  // FFN1 + exact GELU
  GemmP gf1 = {ni, w1T, 4096, 3072, 768, 2,
               b1, nullptr, nullptr, nullptr, nullptr, ffn1o, nullptr, nullptr};
  k_gemm<<<dim3(24, 32), 256, 0, stream>>>(gf1);

  // FFN2 + residual -> d_out (fp32 [2,16,128,768] row-major == [4096][768])
  GemmP gf2 = {ffn1o, w2T, 4096, 768, 3072, 3,
               b2, nullptr, nullptr, resid1, (float*)d_out, nullptr, nullptr, nullptr};
  k_gemm<<<dim3(6, 32), 256, 0, stream>>>(gf2);
}

// Round 3
// 340.305 us; speedup vs baseline: 1.1338x; 1.1338x over previous
//
#include <hip/hip_runtime.h>
#include <cmath>

// ---------------------------------------------------------------------------
// PatchTST encoder layer w/ p-RoPE, MI355X (gfx950).  Round 3:
// Round 2 (async global_load_lds double-buffered staging, 1 barrier/iter,
// LDS-staged coalesced epilogues) + explicit ordering on every same-wave
// LDS write->read path (compiler could reorder type-punned vector loads
// above scalar stores; HW DS is in-order per wave but the optimizer must
// be fenced).
// Fragment layouts (verified, guide §3):
//   A-frag: A[m=lane&15][k=(lane>>4)*8+j] ; B-frag: Bt rows same pattern
//   C/D   : col=lane&15, row=(lane>>4)*4+reg
// ---------------------------------------------------------------------------

typedef __bf16 bf16_t;
typedef bf16_t bf16x8 __attribute__((ext_vector_type(8)));
typedef float floatx4 __attribute__((ext_vector_type(4)));

#define MFMA(a, b, c) __builtin_amdgcn_mfma_f32_16x16x32_bf16((a), (b), (c), 0, 0, 0)

__device__ __forceinline__ bf16_t f2bf(float f) { return (bf16_t)f; }

__device__ __forceinline__ void g2l16(const void* g, void* l) {
  __builtin_amdgcn_global_load_lds(
      (const __attribute__((address_space(1))) unsigned int*)g,
      (__attribute__((address_space(3))) unsigned int*)l, 16, 0, 0);
}

// Wave-level LDS ordering: drain DS pipe + full compiler memory barrier.
__device__ __forceinline__ void lds_fence() {
  asm volatile("s_waitcnt lgkmcnt(0)" ::: "memory");
}

// ---------------------------------------------------------------------------
// Weight transpose + cast: in [R][C] fp32 -> out [C][R] bf16
// ---------------------------------------------------------------------------
struct TC4 { const float* in[4]; bf16_t* out[4]; };

__global__ __launch_bounds__(256) void k_transpose4(TC4 p) {
  const float* in = p.in[blockIdx.z];
  bf16_t* out = p.out[blockIdx.z];
  __shared__ float tile[32][33];
  const int c0 = blockIdx.x * 32, r0 = blockIdx.y * 32;
  const int tx = threadIdx.x & 31, ty = threadIdx.x >> 5;
#pragma unroll
  for (int p4 = 0; p4 < 4; p4++) {
    int r = ty + p4 * 8;
    tile[r][tx] = in[(size_t)(r0 + r) * 768 + c0 + tx];
  }
  __syncthreads();
#pragma unroll
  for (int p4 = 0; p4 < 4; p4++) {
    int r = ty + p4 * 8;
    out[(size_t)(c0 + r) * 768 + r0 + tx] = f2bf(tile[tx][r]);
  }
}

__global__ __launch_bounds__(256) void k_transpose_cast(
    const float* __restrict__ in, bf16_t* __restrict__ out, int R, int C) {
  __shared__ float tile[32][33];
  const int c0 = blockIdx.x * 32, r0 = blockIdx.y * 32;
  const int tx = threadIdx.x & 31, ty = threadIdx.x >> 5;
#pragma unroll
  for (int p4 = 0; p4 < 4; p4++) {
    int r = ty + p4 * 8;
    tile[r][tx] = in[(size_t)(r0 + r) * C + c0 + tx];
  }
  __syncthreads();
#pragma unroll
  for (int p4 = 0; p4 < 4; p4++) {
    int r = ty + p4 * 8;
    out[(size_t)(c0 + r) * R + r0 + tx] = f2bf(tile[tx][r]);
  }
}

// ---------------------------------------------------------------------------
// LayerNorm over 768 cols, fp32 in -> bf16 out. One block (256 thr) per row.
// ---------------------------------------------------------------------------
__global__ __launch_bounds__(256) void k_layernorm(
    const float* __restrict__ x, const float* __restrict__ g,
    const float* __restrict__ b, bf16_t* __restrict__ out) {
  const int row = blockIdx.x;
  const float* xr = x + (size_t)row * 768;
  const int t = threadIdx.x;
  float v0 = xr[t], v1 = xr[t + 256], v2 = xr[t + 512];
  float s = v0 + v1 + v2;
  float s2 = v0 * v0 + v1 * v1 + v2 * v2;
#pragma unroll
  for (int off = 32; off; off >>= 1) {
    s += __shfl_xor(s, off);
    s2 += __shfl_xor(s2, off);
  }
  __shared__ float ra[4], rb[4];
  const int w = t >> 6;
  if ((t & 63) == 0) { ra[w] = s; rb[w] = s2; }
  __syncthreads();
  s = ra[0] + ra[1] + ra[2] + ra[3];
  s2 = rb[0] + rb[1] + rb[2] + rb[3];
  const float mu = s * (1.0f / 768.0f);
  const float var = s2 * (1.0f / 768.0f) - mu * mu;
  const float rstd = rsqrtf(var + 1e-5f);
  bf16_t* orow = out + (size_t)row * 768;
  orow[t]       = f2bf((v0 - mu) * rstd * g[t]       + b[t]);
  orow[t + 256] = f2bf((v1 - mu) * rstd * g[t + 256] + b[t + 256]);
  orow[t + 512] = f2bf((v2 - mu) * rstd * g[t + 512] + b[t + 512]);
}

// ---------------------------------------------------------------------------
// bf16 MFMA GEMM, async double-buffered, 1 barrier/iter.
// C[M,N] = A[M,K] @ Bt[N,K]^T, 128x128 tile, 4 waves (2x2 of 64x64), BK=64.
// ---------------------------------------------------------------------------
struct GemmP {
  const bf16_t* A;
  const bf16_t* Bt;
  int M, N, K, mode;
  const float* bias0;
  const float* bias1;
  const float* bias2;
  const float* resid;
  float* outF;
  bf16_t* outB0;
  bf16_t* outB1;
  bf16_t* outB2;
};

__global__ __launch_bounds__(256, 2) void k_gemm(GemmP p) {
  __shared__ bf16_t lds[32768];  // 64 KiB: lA[2] @0, lB[2] @16384 (elements)
  const int tid = threadIdx.x;
  const int lane = tid & 63, wave = tid >> 6;
  const int quad = lane >> 4, l15 = lane & 15;
  const int wm = (wave >> 1) * 64, wn = (wave & 1) * 64;
  const int m0 = blockIdx.y * 128, n0 = blockIdx.x * 128;

  // ---- staging source pointers (lane-fixed; advance 128B per k-iter) ----
  const char* gA[4];
  const char* gB[4];
#pragma unroll
  for (int pp = 0; pp < 4; pp++) {
    int slot = wave * 256 + pp * 64 + lane;
    int r = slot >> 3;
    int c8 = ((slot & 7) ^ (r & 7)) << 3;
    gA[pp] = (const char*)(p.A + (size_t)(m0 + r) * p.K + c8);
    gB[pp] = (const char*)(p.Bt + (size_t)(n0 + r) * p.K + c8);
  }

  // ---- frag read offsets (elements within a 8192-elem tile; ks=1 -> ^32) --
  int offA[4], offB[4];
#pragma unroll
  for (int i = 0; i < 4; i++) {
    int ra = wm + i * 16 + l15;
    offA[i] = ra * 64 + ((quad * 8) ^ ((ra & 7) << 3));
    int rb = wn + i * 16 + l15;
    offB[i] = rb * 64 + ((quad * 8) ^ ((rb & 7) << 3));
  }

  const floatx4 z4 = {0.f, 0.f, 0.f, 0.f};
  floatx4 acc[4][4];
#pragma unroll
  for (int i = 0; i < 4; i++)
#pragma unroll
    for (int j = 0; j < 4; j++) acc[i][j] = z4;

  const int KT = p.K >> 6;
  // prologue stage -> buf 0
  {
    bf16_t* A0 = lds + wave * 2048;
    bf16_t* B0 = lds + 16384 + wave * 2048;
#pragma unroll
    for (int pp = 0; pp < 4; pp++) {
      g2l16(gA[pp], A0 + pp * 512);
      g2l16(gB[pp], B0 + pp * 512);
    }
  }
  __syncthreads();

  for (int kt = 0; kt < KT; kt++) {
    const int cur = kt & 1;
    if (kt + 1 < KT) {
      const size_t kb = (size_t)(kt + 1) * 128;  // bytes
      bf16_t* A1 = lds + (cur ^ 1) * 8192 + wave * 2048;
      bf16_t* B1 = lds + 16384 + (cur ^ 1) * 8192 + wave * 2048;
#pragma unroll
      for (int pp = 0; pp < 4; pp++) {
        g2l16(gA[pp] + kb, A1 + pp * 512);
        g2l16(gB[pp] + kb, B1 + pp * 512);
      }
    }
    const bf16_t* A0 = lds + cur * 8192;
    const bf16_t* B0 = lds + 16384 + cur * 8192;
#pragma unroll
    for (int ks = 0; ks < 2; ks++) {
      bf16x8 af[4], bfr[4];
#pragma unroll
      for (int i = 0; i < 4; i++) {
        af[i] = *(const bf16x8*)(A0 + (offA[i] ^ (ks * 32)));
        bfr[i] = *(const bf16x8*)(B0 + (offB[i] ^ (ks * 32)));
      }
#pragma unroll
      for (int i = 0; i < 4; i++)
#pragma unroll
        for (int j = 0; j < 4; j++) acc[i][j] = MFMA(af[i], bfr[j], acc[i][j]);
    }
    __syncthreads();  // drains vmcnt (next buf) + all waves done with cur
  }

  // ---- epilogues: stage through per-wave LDS scratch, coalesced stores ----
  // Write phase -> __syncthreads() -> read phase (ordering + safety).
  char* scr = (char*)lds + wave * 16384;

  if (p.mode == 0) {
    const int gnw = n0 + wn;
    const int region = gnw / 768;  // 0=q 1=k 2=v (block-uniform: 768%128==0)
    const int rem = gnw - region * 768;
    const int h = rem >> 6;
    const int b = (m0 + wm) >> 11;
    const int t0 = (m0 + wm) & 2047;
    const float* bias = (region == 0) ? p.bias0 : (region == 1 ? p.bias1 : p.bias2);
    float bb[4];
#pragma unroll
    for (int j = 0; j < 4; j++) bb[j] = bias[h * 64 + j * 16 + l15];
    bf16_t* sb = (bf16_t*)scr;  // [64][72]
    if (region < 2) {
      const float scale = (region == 0) ? 0.125f : 1.0f;
      const float inv_ts = exp2f(-(float)l15 * (13.287712379549449f / 32.0f));
#pragma unroll
      for (int i = 0; i < 4; i++) {
#pragma unroll
        for (int reg = 0; reg < 4; reg++) {
          int tl = i * 16 + quad * 4 + reg;
          float sn, cs;
          sincosf((float)(t0 + tl) * inv_ts, &sn, &cs);
          float v0 = (acc[i][0][reg] + bb[0]) * scale;
          float v1 = (acc[i][1][reg] + bb[1]) * scale;
          float v2 = (acc[i][2][reg] + bb[2]) * scale;
          float v3 = (acc[i][3][reg] + bb[3]) * scale;
          sb[tl * 72 + l15]      = f2bf(v0 * cs - v2 * sn);
          sb[tl * 72 + 16 + l15] = f2bf(v1);
          sb[tl * 72 + 32 + l15] = f2bf(v2 * cs + v0 * sn);
          sb[tl * 72 + 48 + l15] = f2bf(v3);
        }
      }
      __syncthreads();
      bf16_t* outp = (region == 0) ? p.outB0 : p.outB1;
      bf16_t* ob = outp + (((size_t)(b * 12 + h) * 2048 + t0) << 6);
#pragma unroll
      for (int pp = 0; pp < 8; pp++) {
        int row = pp * 8 + (lane >> 3), ch = (lane & 7) << 3;
        *(bf16x8*)(ob + row * 64 + ch) = *(const bf16x8*)&sb[row * 72 + ch];
      }
    } else {
      // V: transpose to [d][t] in scratch, store to vtB [bh][64][2048]
#pragma unroll
      for (int i = 0; i < 4; i++)
#pragma unroll
        for (int j = 0; j < 4; j++)
#pragma unroll
          for (int reg = 0; reg < 4; reg++)
            sb[(j * 16 + l15) * 72 + i * 16 + quad * 4 + reg] =
                f2bf(acc[i][j][reg] + bb[j]);
      __syncthreads();
      bf16_t* ob = p.outB2 + (((size_t)(b * 12 + h)) << 17) + t0;  // *64*2048
#pragma unroll
      for (int pp = 0; pp < 8; pp++) {
        int d = pp * 8 + (lane >> 3), ch = (lane & 7) << 3;
        *(bf16x8*)(ob + (size_t)d * 2048 + ch) = *(const bf16x8*)&sb[d * 72 + ch];
      }
    }
  } else if (p.mode == 2) {
    bf16_t* sb = (bf16_t*)scr;  // [64][72]
    float bb[4];
#pragma unroll
    for (int j = 0; j < 4; j++) bb[j] = p.bias0[n0 + wn + j * 16 + l15];
#pragma unroll
    for (int i = 0; i < 4; i++)
#pragma unroll
      for (int j = 0; j < 4; j++)
#pragma unroll
        for (int reg = 0; reg < 4; reg++) {
          int tl = i * 16 + quad * 4 + reg;
          float x = acc[i][j][reg] + bb[j];
          float gv = 0.5f * x * (1.0f + erff(x * 0.70710678118654752f));
          sb[tl * 72 + j * 16 + l15] = f2bf(gv);
        }
    __syncthreads();
#pragma unroll
    for (int pp = 0; pp < 8; pp++) {
      int row = pp * 8 + (lane >> 3), ch = (lane & 7) << 3;
      *(bf16x8*)(p.outB0 + (size_t)(m0 + wm + row) * p.N + n0 + wn + ch) =
          *(const bf16x8*)&sb[row * 72 + ch];
    }
  } else {  // mode 1 / 3: fp32 out = acc + bias + resid
    float* s4 = (float*)scr;  // [64][64]
#pragma unroll
    for (int i = 0; i < 4; i++)
#pragma unroll
      for (int j = 0; j < 4; j++)
#pragma unroll
        for (int reg = 0; reg < 4; reg++)
          s4[(i * 16 + quad * 4 + reg) * 64 + j * 16 + l15] = acc[i][j][reg];
    __syncthreads();
#pragma unroll
    for (int pp = 0; pp < 16; pp++) {
      int row = pp * 4 + (lane >> 4);
      int cc = l15 * 4;
      floatx4 v = *(const floatx4*)&s4[row * 64 + cc];
      size_t goff = (size_t)(m0 + wm + row) * p.N + n0 + wn + cc;
      floatx4 rv = *(const floatx4*)(p.resid + goff);
      floatx4 bv = *(const floatx4*)(p.bias0 + n0 + wn + cc);
      *(floatx4*)(p.outF + goff) = v + rv + bv;
    }
  }
}

// ---------------------------------------------------------------------------
// Flash attention, async double-buffered, 1 barrier/iter, kv-tile 64.
// Grid (32 q-tiles of 64 rows, 24 b*h), 4 waves x 16 q-rows.
// LDS 40KB: lK[2][64x64] + lV[2][64x64] (V^T) + lP[4][16x64] (wave-private).
// ---------------------------------------------------------------------------
__global__ __launch_bounds__(256, 3) void k_flash(
    const bf16_t* __restrict__ qh, const bf16_t* __restrict__ kh,
    const bf16_t* __restrict__ vt, const float* __restrict__ ab,
    bf16_t* __restrict__ attnA) {
  __shared__ bf16_t sm[20480];  // 40 KiB
  bf16_t* lK = sm;              // [2][4096]
  bf16_t* lV = sm + 8192;       // [2][4096]
  bf16_t* lP = sm + 16384;      // [4][1024]

  const int tid = threadIdx.x, lane = tid & 63, wave = tid >> 6;
  const int quad = lane >> 4, l15 = lane & 15;
  const int qtile = blockIdx.x, bh = blockIdx.y;
  const int h = bh % 12, bq = bh / 12;
  const int qr0 = qtile * 64 + wave * 16;

  const bf16_t* Qb = qh + (size_t)bh * 2048 * 64;
  const bf16_t* Kb = kh + (size_t)bh * 2048 * 64;
  const bf16_t* Vb = vt + (size_t)bh * 64 * 2048;

  // staging source pointers (lane-fixed)
  const char* gK[2];
  const char* gV[2];
#pragma unroll
  for (int pp = 0; pp < 2; pp++) {
    int slot = wave * 128 + pp * 64 + lane;
    int r = slot >> 3;
    int c8 = ((slot & 7) ^ (r & 7)) << 3;
    gK[pp] = (const char*)(Kb + r * 64 + c8);            // + kv*8192 B
    gV[pp] = (const char*)(Vb + (size_t)r * 2048 + c8);  // + kv*128 B
  }

  bf16x8 qf[2];
#pragma unroll
  for (int ks = 0; ks < 2; ks++)
    qf[ks] = *(const bf16x8*)(Qb + (size_t)(qr0 + l15) * 64 + ks * 32 + quad * 8);

  // frag read offsets within a 4096-elem tile (ks=1 -> ^32)
  int offK[4], offV[4];
#pragma unroll
  for (int t4 = 0; t4 < 4; t4++) {
    int sr = t4 * 16 + l15;
    offK[t4] = sr * 64 + ((quad * 8) ^ ((sr & 7) << 3));
    offV[t4] = offK[t4];  // same index form (row = dt*16+l15)
  }
  const int offP = l15 * 64 + ((quad * 8) ^ ((l15 & 7) << 3));

  const floatx4 z4 = {0.f, 0.f, 0.f, 0.f};
  float m_run[4] = {-1e30f, -1e30f, -1e30f, -1e30f};
  float l_run[4] = {0.f, 0.f, 0.f, 0.f};
  floatx4 oacc[4];
#pragma unroll
  for (int dt = 0; dt < 4; dt++) oacc[dt] = z4;

  const float b0 = ab[h * 2], b1 = ab[h * 2 + 1];
  const int myv = qtile >> 1;

  // prologue stage -> buf 0
  {
    bf16_t* K0 = lK + wave * 1024;
    bf16_t* V0 = lV + wave * 1024;
#pragma unroll
    for (int pp = 0; pp < 2; pp++) {
      g2l16(gK[pp], K0 + pp * 512);
      g2l16(gV[pp], V0 + pp * 512);
    }
  }
  __syncthreads();

  for (int kv = 0; kv < 32; kv++) {
    const int cur = kv & 1;
    if (kv + 1 < 32) {
      bf16_t* K1 = lK + (cur ^ 1) * 4096 + wave * 1024;
      bf16_t* V1 = lV + (cur ^ 1) * 4096 + wave * 1024;
      const size_t kb = (size_t)(kv + 1) * 8192, vb = (size_t)(kv + 1) * 128;
#pragma unroll
      for (int pp = 0; pp < 2; pp++) {
        g2l16(gK[pp] + kb, K1 + pp * 512);
        g2l16(gV[pp] + vb, V1 + pp * 512);
      }
    }
    const bf16_t* K0 = lK + cur * 4096;
    const bf16_t* V0 = lV + cur * 4096;

    floatx4 sacc[4] = {z4, z4, z4, z4};
#pragma unroll
    for (int ks = 0; ks < 2; ks++)
#pragma unroll
      for (int ct = 0; ct < 4; ct++)
        sacc[ct] = MFMA(qf[ks], *(const bf16x8*)(K0 + (offK[ct] ^ (ks * 32))),
                        sacc[ct]);

    const float bias = ((kv >> 1) == myv) ? b0 : b1;
    float mnew[4], alpha[4], rs[4];
#pragma unroll
    for (int reg = 0; reg < 4; reg++) {
      float mx = fmaxf(fmaxf(sacc[0][reg], sacc[1][reg]),
                       fmaxf(sacc[2][reg], sacc[3][reg]));
      mx = fmaxf(mx, __shfl_xor(mx, 1));
      mx = fmaxf(mx, __shfl_xor(mx, 2));
      mx = fmaxf(mx, __shfl_xor(mx, 4));
      mx = fmaxf(mx, __shfl_xor(mx, 8));
      mnew[reg] = fmaxf(m_run[reg], mx + bias);
      alpha[reg] = __expf(m_run[reg] - mnew[reg]);
      rs[reg] = 0.f;
    }
#pragma unroll
    for (int ct = 0; ct < 4; ct++)
#pragma unroll
      for (int reg = 0; reg < 4; reg++) {
        float pv = __expf(sacc[ct][reg] + bias - mnew[reg]);
        sacc[ct][reg] = pv;
        rs[reg] += pv;
      }
#pragma unroll
    for (int reg = 0; reg < 4; reg++) {
      rs[reg] += __shfl_xor(rs[reg], 1);
      rs[reg] += __shfl_xor(rs[reg], 2);
      rs[reg] += __shfl_xor(rs[reg], 4);
      rs[reg] += __shfl_xor(rs[reg], 8);
      l_run[reg] = l_run[reg] * alpha[reg] + rs[reg];
      m_run[reg] = mnew[reg];
    }
#pragma unroll
    for (int dt = 0; dt < 4; dt++)
#pragma unroll
      for (int reg = 0; reg < 4; reg++) oacc[dt][reg] *= alpha[reg];

    // P -> wave-private LDS (swizzled); fence before type-punned readback
    bf16_t* myP = lP + wave * 1024;
#pragma unroll
    for (int ct = 0; ct < 4; ct++)
#pragma unroll
      for (int reg = 0; reg < 4; reg++) {
        int r = quad * 4 + reg, s = ct * 16 + l15;
        myP[r * 64 + (((s >> 3) ^ (r & 7)) << 3) + (s & 7)] =
            f2bf(sacc[ct][reg]);
      }
    lds_fence();

#pragma unroll
    for (int ks = 0; ks < 2; ks++) {
      bf16x8 pf = *(const bf16x8*)(myP + (offP ^ (ks * 32)));
#pragma unroll
      for (int dt = 0; dt < 4; dt++)
        oacc[dt] = MFMA(pf, *(const bf16x8*)(V0 + (offV[dt] ^ (ks * 32))),
                        oacc[dt]);
    }
    __syncthreads();  // drains prefetch vmcnt + all waves done with cur
  }

  // epilogue: stage O in wave-private LDS (plain [16][64]), coalesced stores
  bf16_t* myP = lP + wave * 1024;
#pragma unroll
  for (int dt = 0; dt < 4; dt++)
#pragma unroll
    for (int reg = 0; reg < 4; reg++)
      myP[(quad * 4 + reg) * 64 + dt * 16 + l15] =
          f2bf(oacc[dt][reg] / l_run[reg]);
  __syncthreads();
#pragma unroll
  for (int pp = 0; pp < 2; pp++) {
    int row = pp * 8 + (lane >> 3), ch = (lane & 7) << 3;
    *(bf16x8*)(attnA + ((size_t)(bq * 2048 + qr0 + row)) * 768 + h * 64 + ch) =
        *(const bf16x8*)&myP[row * 64 + ch];
  }
}

// ---------------------------------------------------------------------------
extern "C" void kernel_launch(void* const* d_in, const int* in_sizes, int n_in,
                              void* d_out, int out_size, void* d_ws,
                              size_t ws_size, hipStream_t stream) {
  const float* hs  = (const float*)d_in[0];
  const float* wq  = (const float*)d_in[1];
  const float* bq  = (const float*)d_in[2];
  const float* wk  = (const float*)d_in[3];
  const float* bk  = (const float*)d_in[4];
  const float* wv  = (const float*)d_in[5];
  const float* bv  = (const float*)d_in[6];
  const float* wo  = (const float*)d_in[7];
  const float* bo  = (const float*)d_in[8];
  const float* ab  = (const float*)d_in[9];
  const float* g1  = (const float*)d_in[10];
  const float* be1 = (const float*)d_in[11];
  const float* g3  = (const float*)d_in[12];
  const float* be3 = (const float*)d_in[13];
  const float* w1  = (const float*)d_in[14];
  const float* b1  = (const float*)d_in[15];
  const float* w2  = (const float*)d_in[16];
  const float* b2  = (const float*)d_in[17];

  char* ws = (char*)d_ws;
  size_t off = 0;
  auto alloc = [&](size_t bytes) -> void* {
    void* p = ws + off;
    off += (bytes + 255) & ~(size_t)255;
    return p;
  };
  bf16_t* wqkvT = (bf16_t*)alloc((size_t)2304 * 768 * 2);
  bf16_t* woT   = (bf16_t*)alloc((size_t)768 * 768 * 2);
  bf16_t* w1T   = (bf16_t*)alloc((size_t)3072 * 768 * 2);
  bf16_t* w2T   = (bf16_t*)alloc((size_t)768 * 3072 * 2);
  bf16_t* ni    = (bf16_t*)alloc((size_t)4096 * 768 * 2);  // reused for ln3
  bf16_t* qhB   = (bf16_t*)alloc((size_t)24 * 2048 * 64 * 2);
  bf16_t* khB   = (bf16_t*)alloc((size_t)24 * 2048 * 64 * 2);
  bf16_t* vtB   = (bf16_t*)alloc((size_t)24 * 64 * 2048 * 2);
  bf16_t* attnA = (bf16_t*)alloc((size_t)4096 * 768 * 2);
  float*  resid1 = (float*)alloc((size_t)4096 * 768 * 4);
  bf16_t* ffn1o = qhB;  // overlay: q/k/v/attn region dead by FFN1 time

  // weights -> bf16 [N][K]
  TC4 tc;
  tc.in[0] = wq; tc.out[0] = wqkvT;
  tc.in[1] = wk; tc.out[1] = wqkvT + 768 * 768;
  tc.in[2] = wv; tc.out[2] = wqkvT + 2 * 768 * 768;
  tc.in[3] = wo; tc.out[3] = woT;
  k_transpose4<<<dim3(24, 24, 4), 256, 0, stream>>>(tc);
  k_transpose_cast<<<dim3(96, 24), 256, 0, stream>>>(w1, w1T, 768, 3072);
  k_transpose_cast<<<dim3(24, 96), 256, 0, stream>>>(w2, w2T, 3072, 768);

  // LN1
  k_layernorm<<<4096, 256, 0, stream>>>(hs, g1, be1, ni);

  // QKV (fused, N=2304) with bias/scale/rope/head-layout epilogue
  GemmP gqkv = {ni, wqkvT, 4096, 2304, 768, 0,
                bq, bk, bv, nullptr, nullptr, qhB, khB, vtB};
  k_gemm<<<dim3(18, 32), 256, 0, stream>>>(gqkv);

  // flash attention
  k_flash<<<dim3(32, 24), 256, 0, stream>>>(qhB, khB, vtB, ab, attnA);

  // attn @ wo + bo + residual(hidden)
  GemmP gwo = {attnA, woT, 4096, 768, 768, 1,
               bo, nullptr, nullptr, hs, resid1, nullptr, nullptr, nullptr};
  k_gemm<<<dim3(6, 32), 256, 0, stream>>>(gwo);

  // LN3
  k_layernorm<<<4096, 256, 0, stream>>>(resid1, g3, be3, ni);

  // FFN1 + exact GELU
  GemmP gf1 = {ni, w1T, 4096, 3072, 768, 2,
               b1, nullptr, nullptr, nullptr, nullptr, ffn1o, nullptr, nullptr};
  k_gemm<<<dim3(24, 32), 256, 0, stream>>>(gf1);

  // FFN2 + residual -> d_out (fp32 [2,16,128,768] == [4096][768])
  GemmP gf2 = {ffn1o, w2T, 4096, 768, 3072, 3,
               b2, nullptr, nullptr, resid1, (float*)d_out, nullptr, nullptr, nullptr};
  k_gemm<<<dim3(6, 32), 256, 0, stream>>>(gf2);
}

// Round 4
// 294.934 us; speedup vs baseline: 1.3083x; 1.1538x over previous
//
#include <hip/hip_runtime.h>
#include <cmath>

// ---------------------------------------------------------------------------
// PatchTST encoder layer w/ p-RoPE, MI355X (gfx950).  Round 4:
//  - flash softmax rewritten: exp2-domain (Q pre-scaled by 0.125*log2e),
//    NO max subtraction (scores statically bounded ~|3|), bias handled as
//    2 tile-uniform multipliers via dual accumulators, sum reduce deferred
//    to kernel end.  Per-iter softmax = 16 exp2 + 16 adds (was ~32 shfls +
//    alpha/rescale chain).
//  - WO/FFN2 (N=768) moved to 64x64-tile GEMM -> 768 blocks (3/CU), was 192.
//  - transposes + LN1 merged into one k_prep dispatch (10 -> 7 dispatches).
// Fragment layouts (verified): A[m=lane&15][k=quad*8+j]; B from Bt rows;
// C/D col=lane&15,row=quad*4+reg. XOR-swizzled LDS, async global_load_lds.
// ---------------------------------------------------------------------------

typedef __bf16 bf16_t;
typedef bf16_t bf16x8 __attribute__((ext_vector_type(8)));
typedef float floatx4 __attribute__((ext_vector_type(4)));

#define MFMA(a, b, c) __builtin_amdgcn_mfma_f32_16x16x32_bf16((a), (b), (c), 0, 0, 0)
#define LOG2E 1.44269504088896340736f

__device__ __forceinline__ bf16_t f2bf(float f) { return (bf16_t)f; }

__device__ __forceinline__ void g2l16(const void* g, void* l) {
  __builtin_amdgcn_global_load_lds(
      (const __attribute__((address_space(1))) unsigned int*)g,
      (__attribute__((address_space(3))) unsigned int*)l, 16, 0, 0);
}

__device__ __forceinline__ void lds_fence() {
  asm volatile("s_waitcnt lgkmcnt(0)" ::: "memory");
}

// ---------------------------------------------------------------------------
// k_prep: all weight transposes (fp32 [R][C] -> bf16 [C][R]) + LN1, one grid.
// Blocks 0..6911: 32x32 transpose tiles; 6912..11007: LN1 rows.
// ---------------------------------------------------------------------------
struct PrepP {
  const float *wq, *wk, *wv, *wo, *w1, *w2;
  bf16_t *wqkvT, *woT, *w1T, *w2T;
  const float *hs, *g1, *be1;
  bf16_t* ni;
};

__global__ __launch_bounds__(256) void k_prep(PrepP p) {
  __shared__ float shm[32 * 33];
  const int bid = blockIdx.x;
  if (bid < 6912) {
    const float* in;
    bf16_t* out;
    int R, C, tx, ty;
    if (bid < 2304) {
      int m = bid / 576, lo = bid % 576;
      in = (m == 0) ? p.wq : (m == 1) ? p.wk : (m == 2) ? p.wv : p.wo;
      out = (m < 3) ? p.wqkvT + (size_t)m * 768 * 768 : p.woT;
      R = 768; C = 768; tx = lo % 24; ty = lo / 24;
    } else if (bid < 4608) {
      int lo = bid - 2304;
      in = p.w1; out = p.w1T; R = 768; C = 3072; tx = lo % 96; ty = lo / 96;
    } else {
      int lo = bid - 4608;
      in = p.w2; out = p.w2T; R = 3072; C = 768; tx = lo % 24; ty = lo / 24;
    }
    const int c0 = tx * 32, r0 = ty * 32;
    const int lx = threadIdx.x & 31, ly = threadIdx.x >> 5;
#pragma unroll
    for (int p4 = 0; p4 < 4; p4++) {
      int r = ly + p4 * 8;
      shm[r * 33 + lx] = in[(size_t)(r0 + r) * C + c0 + lx];
    }
    __syncthreads();
#pragma unroll
    for (int p4 = 0; p4 < 4; p4++) {
      int r = ly + p4 * 8;
      out[(size_t)(c0 + r) * R + r0 + lx] = f2bf(shm[lx * 33 + r]);
    }
  } else {
    const int row = bid - 6912;
    const float* xr = p.hs + (size_t)row * 768;
    const int t = threadIdx.x;
    float v0 = xr[t], v1 = xr[t + 256], v2 = xr[t + 512];
    float s = v0 + v1 + v2;
    float s2 = v0 * v0 + v1 * v1 + v2 * v2;
#pragma unroll
    for (int off = 32; off; off >>= 1) {
      s += __shfl_xor(s, off);
      s2 += __shfl_xor(s2, off);
    }
    const int w = t >> 6;
    if ((t & 63) == 0) { shm[w] = s; shm[4 + w] = s2; }
    __syncthreads();
    s = shm[0] + shm[1] + shm[2] + shm[3];
    s2 = shm[4] + shm[5] + shm[6] + shm[7];
    const float mu = s * (1.0f / 768.0f);
    const float var = s2 * (1.0f / 768.0f) - mu * mu;
    const float rstd = rsqrtf(var + 1e-5f);
    bf16_t* orow = p.ni + (size_t)row * 768;
    orow[t]       = f2bf((v0 - mu) * rstd * p.g1[t]       + p.be1[t]);
    orow[t + 256] = f2bf((v1 - mu) * rstd * p.g1[t + 256] + p.be1[t + 256]);
    orow[t + 512] = f2bf((v2 - mu) * rstd * p.g1[t + 512] + p.be1[t + 512]);
  }
}

// ---------------------------------------------------------------------------
// LayerNorm (LN3): fp32 in -> bf16 out, one block per row.
// ---------------------------------------------------------------------------
__global__ __launch_bounds__(256) void k_layernorm(
    const float* __restrict__ x, const float* __restrict__ g,
    const float* __restrict__ b, bf16_t* __restrict__ out) {
  const int row = blockIdx.x;
  const float* xr = x + (size_t)row * 768;
  const int t = threadIdx.x;
  float v0 = xr[t], v1 = xr[t + 256], v2 = xr[t + 512];
  float s = v0 + v1 + v2;
  float s2 = v0 * v0 + v1 * v1 + v2 * v2;
#pragma unroll
  for (int off = 32; off; off >>= 1) {
    s += __shfl_xor(s, off);
    s2 += __shfl_xor(s2, off);
  }
  __shared__ float ra[4], rb[4];
  const int w = t >> 6;
  if ((t & 63) == 0) { ra[w] = s; rb[w] = s2; }
  __syncthreads();
  s = ra[0] + ra[1] + ra[2] + ra[3];
  s2 = rb[0] + rb[1] + rb[2] + rb[3];
  const float mu = s * (1.0f / 768.0f);
  const float var = s2 * (1.0f / 768.0f) - mu * mu;
  const float rstd = rsqrtf(var + 1e-5f);
  bf16_t* orow = out + (size_t)row * 768;
  orow[t]       = f2bf((v0 - mu) * rstd * g[t]       + b[t]);
  orow[t + 256] = f2bf((v1 - mu) * rstd * g[t + 256] + b[t + 256]);
  orow[t + 512] = f2bf((v2 - mu) * rstd * g[t + 512] + b[t + 512]);
}

// ---------------------------------------------------------------------------
// 128x128-tile bf16 MFMA GEMM (QKV mode 0, FFN1 mode 2), async dbuf.
// ---------------------------------------------------------------------------
struct GemmP {
  const bf16_t* A;
  const bf16_t* Bt;
  int M, N, K, mode;
  const float* bias0;
  const float* bias1;
  const float* bias2;
  float* outF;
  bf16_t* outB0;
  bf16_t* outB1;
  bf16_t* outB2;
};

__global__ __launch_bounds__(256, 2) void k_gemm(GemmP p) {
  __shared__ bf16_t lds[32768];  // 64 KiB
  const int tid = threadIdx.x;
  const int lane = tid & 63, wave = tid >> 6;
  const int quad = lane >> 4, l15 = lane & 15;
  const int wm = (wave >> 1) * 64, wn = (wave & 1) * 64;
  const int m0 = blockIdx.y * 128, n0 = blockIdx.x * 128;

  const char* gA[4];
  const char* gB[4];
#pragma unroll
  for (int pp = 0; pp < 4; pp++) {
    int slot = wave * 256 + pp * 64 + lane;
    int r = slot >> 3;
    int c8 = ((slot & 7) ^ (r & 7)) << 3;
    gA[pp] = (const char*)(p.A + (size_t)(m0 + r) * p.K + c8);
    gB[pp] = (const char*)(p.Bt + (size_t)(n0 + r) * p.K + c8);
  }

  int offA[4], offB[4];
#pragma unroll
  for (int i = 0; i < 4; i++) {
    int ra = wm + i * 16 + l15;
    offA[i] = ra * 64 + ((quad * 8) ^ ((ra & 7) << 3));
    int rb = wn + i * 16 + l15;
    offB[i] = rb * 64 + ((quad * 8) ^ ((rb & 7) << 3));
  }

  const floatx4 z4 = {0.f, 0.f, 0.f, 0.f};
  floatx4 acc[4][4];
#pragma unroll
  for (int i = 0; i < 4; i++)
#pragma unroll
    for (int j = 0; j < 4; j++) acc[i][j] = z4;

  const int KT = p.K >> 6;
  {
    bf16_t* A0 = lds + wave * 2048;
    bf16_t* B0 = lds + 16384 + wave * 2048;
#pragma unroll
    for (int pp = 0; pp < 4; pp++) {
      g2l16(gA[pp], A0 + pp * 512);
      g2l16(gB[pp], B0 + pp * 512);
    }
  }
  __syncthreads();

  for (int kt = 0; kt < KT; kt++) {
    const int cur = kt & 1;
    if (kt + 1 < KT) {
      const size_t kb = (size_t)(kt + 1) * 128;
      bf16_t* A1 = lds + (cur ^ 1) * 8192 + wave * 2048;
      bf16_t* B1 = lds + 16384 + (cur ^ 1) * 8192 + wave * 2048;
#pragma unroll
      for (int pp = 0; pp < 4; pp++) {
        g2l16(gA[pp] + kb, A1 + pp * 512);
        g2l16(gB[pp] + kb, B1 + pp * 512);
      }
    }
    const bf16_t* A0 = lds + cur * 8192;
    const bf16_t* B0 = lds + 16384 + cur * 8192;
#pragma unroll
    for (int ks = 0; ks < 2; ks++) {
      bf16x8 af[4], bfr[4];
#pragma unroll
      for (int i = 0; i < 4; i++) {
        af[i] = *(const bf16x8*)(A0 + (offA[i] ^ (ks * 32)));
        bfr[i] = *(const bf16x8*)(B0 + (offB[i] ^ (ks * 32)));
      }
#pragma unroll
      for (int i = 0; i < 4; i++)
#pragma unroll
        for (int j = 0; j < 4; j++) acc[i][j] = MFMA(af[i], bfr[j], acc[i][j]);
    }
    __syncthreads();
  }

  char* scr = (char*)lds + wave * 16384;

  if (p.mode == 0) {
    const int gnw = n0 + wn;
    const int region = gnw / 768;  // block-uniform
    const int rem = gnw - region * 768;
    const int h = rem >> 6;
    const int b = (m0 + wm) >> 11;
    const int t0 = (m0 + wm) & 2047;
    const float* bias = (region == 0) ? p.bias0 : (region == 1 ? p.bias1 : p.bias2);
    float bb[4];
#pragma unroll
    for (int j = 0; j < 4; j++) bb[j] = bias[h * 64 + j * 16 + l15];
    bf16_t* sb = (bf16_t*)scr;  // [64][72]
    if (region < 2) {
      // q gets 0.125 * log2(e) folded in (flash works in exp2 domain)
      const float scale = (region == 0) ? 0.125f * LOG2E : 1.0f;
      const float inv_ts = exp2f(-(float)l15 * (13.287712379549449f / 32.0f));
#pragma unroll
      for (int i = 0; i < 4; i++) {
#pragma unroll
        for (int reg = 0; reg < 4; reg++) {
          int tl = i * 16 + quad * 4 + reg;
          float sn, cs;
          __sincosf((float)(t0 + tl) * inv_ts, &sn, &cs);
          float v0 = (acc[i][0][reg] + bb[0]) * scale;
          float v1 = (acc[i][1][reg] + bb[1]) * scale;
          float v2 = (acc[i][2][reg] + bb[2]) * scale;
          float v3 = (acc[i][3][reg] + bb[3]) * scale;
          sb[tl * 72 + l15]      = f2bf(v0 * cs - v2 * sn);
          sb[tl * 72 + 16 + l15] = f2bf(v1);
          sb[tl * 72 + 32 + l15] = f2bf(v2 * cs + v0 * sn);
          sb[tl * 72 + 48 + l15] = f2bf(v3);
        }
      }
      __syncthreads();
      bf16_t* outp = (region == 0) ? p.outB0 : p.outB1;
      bf16_t* ob = outp + (((size_t)(b * 12 + h) * 2048 + t0) << 6);
#pragma unroll
      for (int pp = 0; pp < 8; pp++) {
        int row = pp * 8 + (lane >> 3), ch = (lane & 7) << 3;
        *(bf16x8*)(ob + row * 64 + ch) = *(const bf16x8*)&sb[row * 72 + ch];
      }
    } else {
#pragma unroll
      for (int i = 0; i < 4; i++)
#pragma unroll
        for (int j = 0; j < 4; j++)
#pragma unroll
          for (int reg = 0; reg < 4; reg++)
            sb[(j * 16 + l15) * 72 + i * 16 + quad * 4 + reg] =
                f2bf(acc[i][j][reg] + bb[j]);
      __syncthreads();
      bf16_t* ob = p.outB2 + (((size_t)(b * 12 + h)) << 17) + t0;
#pragma unroll
      for (int pp = 0; pp < 8; pp++) {
        int d = pp * 8 + (lane >> 3), ch = (lane & 7) << 3;
        *(bf16x8*)(ob + (size_t)d * 2048 + ch) = *(const bf16x8*)&sb[d * 72 + ch];
      }
    }
  } else {  // mode 2: FFN1 + exact GELU -> bf16
    bf16_t* sb = (bf16_t*)scr;  // [64][72]
    float bb[4];
#pragma unroll
    for (int j = 0; j < 4; j++) bb[j] = p.bias0[n0 + wn + j * 16 + l15];
#pragma unroll
    for (int i = 0; i < 4; i++)
#pragma unroll
      for (int j = 0; j < 4; j++)
#pragma unroll
        for (int reg = 0; reg < 4; reg++) {
          int tl = i * 16 + quad * 4 + reg;
          float x = acc[i][j][reg] + bb[j];
          float gv = 0.5f * x * (1.0f + erff(x * 0.70710678118654752f));
          sb[tl * 72 + j * 16 + l15] = f2bf(gv);
        }
    __syncthreads();
#pragma unroll
    for (int pp = 0; pp < 8; pp++) {
      int row = pp * 8 + (lane >> 3), ch = (lane & 7) << 3;
      *(bf16x8*)(p.outB0 + (size_t)(m0 + wm + row) * p.N + n0 + wn + ch) =
          *(const bf16x8*)&sb[row * 72 + ch];
    }
  }
}

// ---------------------------------------------------------------------------
// 64x64-tile GEMM for N=768 layers (WO, FFN2): fp32 out = acc + bias + resid.
// 768 blocks (3/CU). 4 waves, each 32x32. BK=64, async dbuf, 32 KiB LDS.
// ---------------------------------------------------------------------------
__global__ __launch_bounds__(256, 3) void k_gemm64(
    const bf16_t* __restrict__ A, const bf16_t* __restrict__ Bt, int N, int K,
    const float* __restrict__ bias, const float* __restrict__ resid,
    float* __restrict__ outF) {
  __shared__ bf16_t lds[16384];  // 32 KiB: lA[2][4096] @0, lB[2][4096] @8192
  const int tid = threadIdx.x;
  const int lane = tid & 63, wave = tid >> 6;
  const int quad = lane >> 4, l15 = lane & 15;
  const int wm = (wave >> 1) * 32, wn = (wave & 1) * 32;
  const int m0 = blockIdx.y * 64, n0 = blockIdx.x * 64;

  const char* gA[2];
  const char* gB[2];
#pragma unroll
  for (int pp = 0; pp < 2; pp++) {
    int slot = wave * 128 + pp * 64 + lane;
    int r = slot >> 3;
    int c8 = ((slot & 7) ^ (r & 7)) << 3;
    gA[pp] = (const char*)(A + (size_t)(m0 + r) * K + c8);
    gB[pp] = (const char*)(Bt + (size_t)(n0 + r) * K + c8);
  }

  int offA[2], offB[2];
#pragma unroll
  for (int i = 0; i < 2; i++) {
    int ra = wm + i * 16 + l15;
    offA[i] = ra * 64 + ((quad * 8) ^ ((ra & 7) << 3));
    int rb = wn + i * 16 + l15;
    offB[i] = rb * 64 + ((quad * 8) ^ ((rb & 7) << 3));
  }

  const floatx4 z4 = {0.f, 0.f, 0.f, 0.f};
  floatx4 acc[2][2];
#pragma unroll
  for (int i = 0; i < 2; i++)
#pragma unroll
    for (int j = 0; j < 2; j++) acc[i][j] = z4;

  const int KT = K >> 6;
  {
    bf16_t* A0 = lds + wave * 1024;
    bf16_t* B0 = lds + 8192 + wave * 1024;
#pragma unroll
    for (int pp = 0; pp < 2; pp++) {
      g2l16(gA[pp], A0 + pp * 512);
      g2l16(gB[pp], B0 + pp * 512);
    }
  }
  __syncthreads();

  for (int kt = 0; kt < KT; kt++) {
    const int cur = kt & 1;
    if (kt + 1 < KT) {
      const size_t kb = (size_t)(kt + 1) * 128;
      bf16_t* A1 = lds + (cur ^ 1) * 4096 + wave * 1024;
      bf16_t* B1 = lds + 8192 + (cur ^ 1) * 4096 + wave * 1024;
#pragma unroll
      for (int pp = 0; pp < 2; pp++) {
        g2l16(gA[pp] + kb, A1 + pp * 512);
        g2l16(gB[pp] + kb, B1 + pp * 512);
      }
    }
    const bf16_t* A0 = lds + cur * 4096;
    const bf16_t* B0 = lds + 8192 + cur * 4096;
#pragma unroll
    for (int ks = 0; ks < 2; ks++) {
      bf16x8 af[2], bfr[2];
#pragma unroll
      for (int i = 0; i < 2; i++) {
        af[i] = *(const bf16x8*)(A0 + (offA[i] ^ (ks * 32)));
        bfr[i] = *(const bf16x8*)(B0 + (offB[i] ^ (ks * 32)));
      }
#pragma unroll
      for (int i = 0; i < 2; i++)
#pragma unroll
        for (int j = 0; j < 2; j++) acc[i][j] = MFMA(af[i], bfr[j], acc[i][j]);
    }
    __syncthreads();
  }

  // epilogue: per-wave fp32 [32][32] scratch -> coalesced float4 stores
  float* s4 = (float*)lds + wave * 1024;
#pragma unroll
  for (int i = 0; i < 2; i++)
#pragma unroll
    for (int j = 0; j < 2; j++)
#pragma unroll
      for (int reg = 0; reg < 4; reg++)
        s4[(i * 16 + quad * 4 + reg) * 32 + j * 16 + l15] = acc[i][j][reg];
  __syncthreads();
#pragma unroll
  for (int pp = 0; pp < 4; pp++) {
    int row = pp * 8 + (lane >> 3);
    int c4 = (lane & 7) * 4;
    floatx4 v = *(const floatx4*)&s4[row * 32 + c4];
    size_t goff = (size_t)(m0 + wm + row) * N + n0 + wn + c4;
    floatx4 rv = *(const floatx4*)(resid + goff);
    floatx4 bv = *(const floatx4*)(bias + n0 + wn + c4);
    *(floatx4*)(outF + goff) = v + rv + bv;
  }
}

// ---------------------------------------------------------------------------
// Flash attention, exp2-domain, no max subtraction, dual accumulators for
// the 2-valued variate bias. Async dbuf staging, 1 barrier/iter, kv-tile 64.
// ---------------------------------------------------------------------------
__global__ __launch_bounds__(256, 3) void k_flash(
    const bf16_t* __restrict__ qh, const bf16_t* __restrict__ kh,
    const bf16_t* __restrict__ vt, const float* __restrict__ ab,
    bf16_t* __restrict__ attnA) {
  __shared__ bf16_t sm[20480];  // 40 KiB
  bf16_t* lK = sm;              // [2][4096]
  bf16_t* lV = sm + 8192;       // [2][4096]
  bf16_t* lP = sm + 16384;      // [4][1024] wave-private

  const int tid = threadIdx.x, lane = tid & 63, wave = tid >> 6;
  const int quad = lane >> 4, l15 = lane & 15;
  const int qtile = blockIdx.x, bh = blockIdx.y;
  const int h = bh % 12, bq = bh / 12;
  const int qr0 = qtile * 64 + wave * 16;

  const bf16_t* Qb = qh + (size_t)bh * 2048 * 64;
  const bf16_t* Kb = kh + (size_t)bh * 2048 * 64;
  const bf16_t* Vb = vt + (size_t)bh * 64 * 2048;

  const char* gK[2];
  const char* gV[2];
#pragma unroll
  for (int pp = 0; pp < 2; pp++) {
    int slot = wave * 128 + pp * 64 + lane;
    int r = slot >> 3;
    int c8 = ((slot & 7) ^ (r & 7)) << 3;
    gK[pp] = (const char*)(Kb + r * 64 + c8);
    gV[pp] = (const char*)(Vb + (size_t)r * 2048 + c8);
  }

  bf16x8 qf[2];
#pragma unroll
  for (int ks = 0; ks < 2; ks++)
    qf[ks] = *(const bf16x8*)(Qb + (size_t)(qr0 + l15) * 64 + ks * 32 + quad * 8);

  int offK[4];
#pragma unroll
  for (int t4 = 0; t4 < 4; t4++) {
    int sr = t4 * 16 + l15;
    offK[t4] = sr * 64 + ((quad * 8) ^ ((sr & 7) << 3));
  }
  const int offP = l15 * 64 + ((quad * 8) ^ ((l15 & 7) << 3));

  const floatx4 z4 = {0.f, 0.f, 0.f, 0.f};
  float l_all[4] = {0.f, 0.f, 0.f, 0.f};
  float l_same[4] = {0.f, 0.f, 0.f, 0.f};
  floatx4 oacc[4], osame[4];
#pragma unroll
  for (int dt = 0; dt < 4; dt++) { oacc[dt] = z4; osame[dt] = z4; }

  const float f_s = exp2f(ab[h * 2] * LOG2E);
  const float f_d = exp2f(ab[h * 2 + 1] * LOG2E);
  const int myv = qtile >> 1;

  {
    bf16_t* K0 = lK + wave * 1024;
    bf16_t* V0 = lV + wave * 1024;
#pragma unroll
    for (int pp = 0; pp < 2; pp++) {
      g2l16(gK[pp], K0 + pp * 512);
      g2l16(gV[pp], V0 + pp * 512);
    }
  }
  __syncthreads();

  for (int kv = 0; kv < 32; kv++) {
    const int cur = kv & 1;
    if (kv + 1 < 32) {
      bf16_t* K1 = lK + (cur ^ 1) * 4096 + wave * 1024;
      bf16_t* V1 = lV + (cur ^ 1) * 4096 + wave * 1024;
      const size_t kb = (size_t)(kv + 1) * 8192, vb = (size_t)(kv + 1) * 128;
#pragma unroll
      for (int pp = 0; pp < 2; pp++) {
        g2l16(gK[pp] + kb, K1 + pp * 512);
        g2l16(gV[pp] + vb, V1 + pp * 512);
      }
    }
    const bf16_t* K0 = lK + cur * 4096;
    const bf16_t* V0 = lV + cur * 4096;

    floatx4 sacc[4] = {z4, z4, z4, z4};
#pragma unroll
    for (int ks = 0; ks < 2; ks++)
#pragma unroll
      for (int ct = 0; ct < 4; ct++)
        sacc[ct] = MFMA(qf[ks], *(const bf16x8*)(K0 + (offK[ct] ^ (ks * 32))),
                        sacc[ct]);

    const bool same = ((kv >> 1) == myv);  // block-uniform

    // P = exp2(s') ; accumulate row sums per-lane (reduce deferred to end)
#pragma unroll
    for (int ct = 0; ct < 4; ct++)
#pragma unroll
      for (int reg = 0; reg < 4; reg++) {
        float pv = exp2f(sacc[ct][reg]);
        sacc[ct][reg] = pv;
        l_all[reg] += pv;
      }
    if (same) {
#pragma unroll
      for (int ct = 0; ct < 4; ct++)
#pragma unroll
        for (int reg = 0; reg < 4; reg++) l_same[reg] += sacc[ct][reg];
    }

    bf16_t* myP = lP + wave * 1024;
#pragma unroll
    for (int ct = 0; ct < 4; ct++)
#pragma unroll
      for (int reg = 0; reg < 4; reg++) {
        int r = quad * 4 + reg, s = ct * 16 + l15;
        myP[r * 64 + (((s >> 3) ^ (r & 7)) << 3) + (s & 7)] =
            f2bf(sacc[ct][reg]);
      }
    lds_fence();

    bf16x8 pf[2];
#pragma unroll
    for (int ks = 0; ks < 2; ks++)
      pf[ks] = *(const bf16x8*)(myP + (offP ^ (ks * 32)));
#pragma unroll
    for (int ks = 0; ks < 2; ks++)
#pragma unroll
      for (int dt = 0; dt < 4; dt++)
        oacc[dt] = MFMA(pf[ks], *(const bf16x8*)(V0 + (offK[dt] ^ (ks * 32))),
                        oacc[dt]);
    if (same) {
#pragma unroll
      for (int ks = 0; ks < 2; ks++)
#pragma unroll
        for (int dt = 0; dt < 4; dt++)
          osame[dt] = MFMA(pf[ks], *(const bf16x8*)(V0 + (offK[dt] ^ (ks * 32))),
                           osame[dt]);
    }
    __syncthreads();
  }

  // final: cross-lane reduce l, combine bias factors, normalize, store
  const float df = f_s - f_d;
  float inv_l[4];
#pragma unroll
  for (int reg = 0; reg < 4; reg++) {
    float la = l_all[reg], ls = l_same[reg];
    la += __shfl_xor(la, 1); la += __shfl_xor(la, 2);
    la += __shfl_xor(la, 4); la += __shfl_xor(la, 8);
    ls += __shfl_xor(ls, 1); ls += __shfl_xor(ls, 2);
    ls += __shfl_xor(ls, 4); ls += __shfl_xor(ls, 8);
    inv_l[reg] = 1.0f / (f_d * la + df * ls);
  }

  bf16_t* myP = lP + wave * 1024;
#pragma unroll
  for (int dt = 0; dt < 4; dt++)
#pragma unroll
    for (int reg = 0; reg < 4; reg++)
      myP[(quad * 4 + reg) * 64 + dt * 16 + l15] =
          f2bf((f_d * oacc[dt][reg] + df * osame[dt][reg]) * inv_l[reg]);
  __syncthreads();
#pragma unroll
  for (int pp = 0; pp < 2; pp++) {
    int row = pp * 8 + (lane >> 3), ch = (lane & 7) << 3;
    *(bf16x8*)(attnA + ((size_t)(bq * 2048 + qr0 + row)) * 768 + h * 64 + ch) =
        *(const bf16x8*)&myP[row * 64 + ch];
  }
}

// ---------------------------------------------------------------------------
extern "C" void kernel_launch(void* const* d_in, const int* in_sizes, int n_in,
                              void* d_out, int out_size, void* d_ws,
                              size_t ws_size, hipStream_t stream) {
  const float* hs  = (const float*)d_in[0];
  const float* wq  = (const float*)d_in[1];
  const float* bq  = (const float*)d_in[2];
  const float* wk  = (const float*)d_in[3];
  const float* bk  = (const float*)d_in[4];
  const float* wv  = (const float*)d_in[5];
  const float* bv  = (const float*)d_in[6];
  const float* wo  = (const float*)d_in[7];
  const float* bo  = (const float*)d_in[8];
  const float* ab  = (const float*)d_in[9];
  const float* g1  = (const float*)d_in[10];
  const float* be1 = (const float*)d_in[11];
  const float* g3  = (const float*)d_in[12];
  const float* be3 = (const float*)d_in[13];
  const float* w1  = (const float*)d_in[14];
  const float* b1  = (const float*)d_in[15];
  const float* w2  = (const float*)d_in[16];
  const float* b2  = (const float*)d_in[17];

  char* ws = (char*)d_ws;
  size_t off = 0;
  auto alloc = [&](size_t bytes) -> void* {
    void* p = ws + off;
    off += (bytes + 255) & ~(size_t)255;
    return p;
  };
  bf16_t* wqkvT = (bf16_t*)alloc((size_t)2304 * 768 * 2);
  bf16_t* woT   = (bf16_t*)alloc((size_t)768 * 768 * 2);
  bf16_t* w1T   = (bf16_t*)alloc((size_t)3072 * 768 * 2);
  bf16_t* w2T   = (bf16_t*)alloc((size_t)768 * 3072 * 2);
  bf16_t* ni    = (bf16_t*)alloc((size_t)4096 * 768 * 2);
  bf16_t* qhB   = (bf16_t*)alloc((size_t)24 * 2048 * 64 * 2);
  bf16_t* khB   = (bf16_t*)alloc((size_t)24 * 2048 * 64 * 2);
  bf16_t* vtB   = (bf16_t*)alloc((size_t)24 * 64 * 2048 * 2);
  bf16_t* attnA = (bf16_t*)alloc((size_t)4096 * 768 * 2);
  float*  resid1 = (float*)alloc((size_t)4096 * 768 * 4);
  bf16_t* ffn1o = qhB;  // overlay: q/k/v/attn region dead by FFN1 time

  // prep: all transposes + LN1, one dispatch
  PrepP pp = {wq, wk, wv, wo, w1, w2, wqkvT, woT, w1T, w2T, hs, g1, be1, ni};
  k_prep<<<11008, 256, 0, stream>>>(pp);

  // QKV (fused, N=2304): bias, q*0.125*log2e, p-RoPE, head-layout scatter
  GemmP gqkv = {ni, wqkvT, 4096, 2304, 768, 0,
                bq, bk, bv, nullptr, qhB, khB, vtB};
  k_gemm<<<dim3(18, 32), 256, 0, stream>>>(gqkv);

  // flash attention (exp2 domain)
  k_flash<<<dim3(32, 24), 256, 0, stream>>>(qhB, khB, vtB, ab, attnA);

  // attn @ wo + bo + residual(hidden) -> resid1 (fp32)
  k_gemm64<<<dim3(12, 64), 256, 0, stream>>>(attnA, woT, 768, 768, bo, hs,
                                             resid1);

  // LN3
  k_layernorm<<<4096, 256, 0, stream>>>(resid1, g3, be3, ni);

  // FFN1 + exact GELU -> bf16
  GemmP gf1 = {ni, w1T, 4096, 3072, 768, 2,
               b1, nullptr, nullptr, nullptr, ffn1o, nullptr, nullptr};
  k_gemm<<<dim3(24, 32), 256, 0, stream>>>(gf1);

  // FFN2 + b2 + residual -> d_out (fp32 [4096][768])
  k_gemm64<<<dim3(12, 64), 256, 0, stream>>>(ffn1o, w2T, 768, 3072, b2,
                                             resid1, (float*)d_out);
}

// Round 5
// 290.757 us; speedup vs baseline: 1.3270x; 1.0144x over previous
//
#include <hip/hip_runtime.h>
#include <cmath>

// ---------------------------------------------------------------------------
// PatchTST encoder layer w/ p-RoPE, MI355X (gfx950).  Round 5:
//  - k_gemm: m97 structure (single 32KB staging buffer, 2 barriers/iter,
//    epilogue scratch OVERLAYS staging -> 36KB LDS, launch_bounds(256,3)
//    -> 12-16 waves/CU, was 8 with the 64KB dbuf).
//  - k_gemm64: single-buffer BK=128 (16 MFMA per barrier pair, was 8),
//    32KB LDS, launch_bounds(256,4).
//  - flash: variate bias folded additively into exp2 arg (tile-uniform) ->
//    osame/l_same accumulators deleted.
// Fragment layouts (verified): A[m=lane&15][k=quad*8+j]; B from Bt rows;
// C/D col=lane&15,row=quad*4+reg. XOR-swizzled LDS, async global_load_lds.
// ---------------------------------------------------------------------------

typedef __bf16 bf16_t;
typedef bf16_t bf16x8 __attribute__((ext_vector_type(8)));
typedef float floatx4 __attribute__((ext_vector_type(4)));

#define MFMA(a, b, c) __builtin_amdgcn_mfma_f32_16x16x32_bf16((a), (b), (c), 0, 0, 0)
#define LOG2E 1.44269504088896340736f

__device__ __forceinline__ bf16_t f2bf(float f) { return (bf16_t)f; }

__device__ __forceinline__ void g2l16(const void* g, void* l) {
  __builtin_amdgcn_global_load_lds(
      (const __attribute__((address_space(1))) unsigned int*)g,
      (__attribute__((address_space(3))) unsigned int*)l, 16, 0, 0);
}

__device__ __forceinline__ void lds_fence() {
  asm volatile("s_waitcnt lgkmcnt(0)" ::: "memory");
}

// ---------------------------------------------------------------------------
// k_prep: all weight transposes (fp32 [R][C] -> bf16 [C][R]) + LN1, one grid.
// ---------------------------------------------------------------------------
struct PrepP {
  const float *wq, *wk, *wv, *wo, *w1, *w2;
  bf16_t *wqkvT, *woT, *w1T, *w2T;
  const float *hs, *g1, *be1;
  bf16_t* ni;
};

__global__ __launch_bounds__(256) void k_prep(PrepP p) {
  __shared__ float shm[32 * 33];
  const int bid = blockIdx.x;
  if (bid < 6912) {
    const float* in;
    bf16_t* out;
    int R, C, tx, ty;
    if (bid < 2304) {
      int m = bid / 576, lo = bid % 576;
      in = (m == 0) ? p.wq : (m == 1) ? p.wk : (m == 2) ? p.wv : p.wo;
      out = (m < 3) ? p.wqkvT + (size_t)m * 768 * 768 : p.woT;
      R = 768; C = 768; tx = lo % 24; ty = lo / 24;
    } else if (bid < 4608) {
      int lo = bid - 2304;
      in = p.w1; out = p.w1T; R = 768; C = 3072; tx = lo % 96; ty = lo / 96;
    } else {
      int lo = bid - 4608;
      in = p.w2; out = p.w2T; R = 3072; C = 768; tx = lo % 24; ty = lo / 24;
    }
    const int c0 = tx * 32, r0 = ty * 32;
    const int lx = threadIdx.x & 31, ly = threadIdx.x >> 5;
#pragma unroll
    for (int p4 = 0; p4 < 4; p4++) {
      int r = ly + p4 * 8;
      shm[r * 33 + lx] = in[(size_t)(r0 + r) * C + c0 + lx];
    }
    __syncthreads();
#pragma unroll
    for (int p4 = 0; p4 < 4; p4++) {
      int r = ly + p4 * 8;
      out[(size_t)(c0 + r) * R + r0 + lx] = f2bf(shm[lx * 33 + r]);
    }
  } else {
    const int row = bid - 6912;
    const float* xr = p.hs + (size_t)row * 768;
    const int t = threadIdx.x;
    float v0 = xr[t], v1 = xr[t + 256], v2 = xr[t + 512];
    float s = v0 + v1 + v2;
    float s2 = v0 * v0 + v1 * v1 + v2 * v2;
#pragma unroll
    for (int off = 32; off; off >>= 1) {
      s += __shfl_xor(s, off);
      s2 += __shfl_xor(s2, off);
    }
    const int w = t >> 6;
    if ((t & 63) == 0) { shm[w] = s; shm[4 + w] = s2; }
    __syncthreads();
    s = shm[0] + shm[1] + shm[2] + shm[3];
    s2 = shm[4] + shm[5] + shm[6] + shm[7];
    const float mu = s * (1.0f / 768.0f);
    const float var = s2 * (1.0f / 768.0f) - mu * mu;
    const float rstd = rsqrtf(var + 1e-5f);
    bf16_t* orow = p.ni + (size_t)row * 768;
    orow[t]       = f2bf((v0 - mu) * rstd * p.g1[t]       + p.be1[t]);
    orow[t + 256] = f2bf((v1 - mu) * rstd * p.g1[t + 256] + p.be1[t + 256]);
    orow[t + 512] = f2bf((v2 - mu) * rstd * p.g1[t + 512] + p.be1[t + 512]);
  }
}

// ---------------------------------------------------------------------------
// LayerNorm (LN3): fp32 in -> bf16 out, one block per row.
// ---------------------------------------------------------------------------
__global__ __launch_bounds__(256) void k_layernorm(
    const float* __restrict__ x, const float* __restrict__ g,
    const float* __restrict__ b, bf16_t* __restrict__ out) {
  const int row = blockIdx.x;
  const float* xr = x + (size_t)row * 768;
  const int t = threadIdx.x;
  float v0 = xr[t], v1 = xr[t + 256], v2 = xr[t + 512];
  float s = v0 + v1 + v2;
  float s2 = v0 * v0 + v1 * v1 + v2 * v2;
#pragma unroll
  for (int off = 32; off; off >>= 1) {
    s += __shfl_xor(s, off);
    s2 += __shfl_xor(s2, off);
  }
  __shared__ float ra[4], rb[4];
  const int w = t >> 6;
  if ((t & 63) == 0) { ra[w] = s; rb[w] = s2; }
  __syncthreads();
  s = ra[0] + ra[1] + ra[2] + ra[3];
  s2 = rb[0] + rb[1] + rb[2] + rb[3];
  const float mu = s * (1.0f / 768.0f);
  const float var = s2 * (1.0f / 768.0f) - mu * mu;
  const float rstd = rsqrtf(var + 1e-5f);
  bf16_t* orow = out + (size_t)row * 768;
  orow[t]       = f2bf((v0 - mu) * rstd * g[t]       + b[t]);
  orow[t + 256] = f2bf((v1 - mu) * rstd * g[t + 256] + b[t + 256]);
  orow[t + 512] = f2bf((v2 - mu) * rstd * g[t + 512] + b[t + 512]);
}

// ---------------------------------------------------------------------------
// 128x128-tile bf16 MFMA GEMM (QKV mode 0, FFN1 mode 2).
// m97 structure: single 32KB staging buffer, stage -> sync -> compute -> sync.
// Epilogue scratch (9216 B/wave) overlays staging. 36 KB LDS, 3-4 blocks/CU.
// ---------------------------------------------------------------------------
struct GemmP {
  const bf16_t* A;
  const bf16_t* Bt;
  int M, N, K, mode;
  const float* bias0;
  const float* bias1;
  const float* bias2;
  float* outF;
  bf16_t* outB0;
  bf16_t* outB1;
  bf16_t* outB2;
};

__global__ __launch_bounds__(256, 3) void k_gemm(GemmP p) {
  __shared__ bf16_t lds[18432];  // 36 KiB: lA@0[8192], lB@8192[8192] + scratch
  const int tid = threadIdx.x;
  const int lane = tid & 63, wave = tid >> 6;
  const int quad = lane >> 4, l15 = lane & 15;
  const int wm = (wave >> 1) * 64, wn = (wave & 1) * 64;
  const int m0 = blockIdx.y * 128, n0 = blockIdx.x * 128;

  const char* gA[4];
  const char* gB[4];
#pragma unroll
  for (int pp = 0; pp < 4; pp++) {
    int slot = wave * 256 + pp * 64 + lane;
    int r = slot >> 3;
    int c8 = ((slot & 7) ^ (r & 7)) << 3;
    gA[pp] = (const char*)(p.A + (size_t)(m0 + r) * p.K + c8);
    gB[pp] = (const char*)(p.Bt + (size_t)(n0 + r) * p.K + c8);
  }

  int offA[4], offB[4];
#pragma unroll
  for (int i = 0; i < 4; i++) {
    int ra = wm + i * 16 + l15;
    offA[i] = ra * 64 + ((quad * 8) ^ ((ra & 7) << 3));
    int rb = wn + i * 16 + l15;
    offB[i] = rb * 64 + ((quad * 8) ^ ((rb & 7) << 3));
  }

  const floatx4 z4 = {0.f, 0.f, 0.f, 0.f};
  floatx4 acc[4][4];
#pragma unroll
  for (int i = 0; i < 4; i++)
#pragma unroll
    for (int j = 0; j < 4; j++) acc[i][j] = z4;

  const int KT = p.K >> 6;
  bf16_t* Ad = lds + wave * 2048;
  bf16_t* Bd = lds + 8192 + wave * 2048;

  for (int kt = 0; kt < KT; kt++) {
    const size_t kb = (size_t)kt * 128;  // bytes
#pragma unroll
    for (int pp = 0; pp < 4; pp++) {
      g2l16(gA[pp] + kb, Ad + pp * 512);
      g2l16(gB[pp] + kb, Bd + pp * 512);
    }
    __syncthreads();  // drains vmcnt: tile visible to all
#pragma unroll
    for (int ks = 0; ks < 2; ks++) {
      bf16x8 af[4], bfr[4];
#pragma unroll
      for (int i = 0; i < 4; i++) {
        af[i] = *(const bf16x8*)(lds + (offA[i] ^ (ks * 32)));
        bfr[i] = *(const bf16x8*)(lds + 8192 + (offB[i] ^ (ks * 32)));
      }
#pragma unroll
      for (int i = 0; i < 4; i++)
#pragma unroll
        for (int j = 0; j < 4; j++) acc[i][j] = MFMA(af[i], bfr[j], acc[i][j]);
    }
    __syncthreads();  // all waves done reading before restage
  }

  // ---- epilogues: per-wave LDS scratch (overlays staging), coalesced ----
  char* scr = (char*)lds + wave * 9216;

  if (p.mode == 0) {
    const int gnw = n0 + wn;
    const int region = gnw / 768;  // block-uniform
    const int rem = gnw - region * 768;
    const int h = rem >> 6;
    const int b = (m0 + wm) >> 11;
    const int t0 = (m0 + wm) & 2047;
    const float* bias = (region == 0) ? p.bias0 : (region == 1 ? p.bias1 : p.bias2);
    float bb[4];
#pragma unroll
    for (int j = 0; j < 4; j++) bb[j] = bias[h * 64 + j * 16 + l15];
    bf16_t* sb = (bf16_t*)scr;  // [64][72]
    if (region < 2) {
      // q gets 0.125 * log2(e) folded in (flash works in exp2 domain)
      const float scale = (region == 0) ? 0.125f * LOG2E : 1.0f;
      const float inv_ts = exp2f(-(float)l15 * (13.287712379549449f / 32.0f));
#pragma unroll
      for (int i = 0; i < 4; i++) {
#pragma unroll
        for (int reg = 0; reg < 4; reg++) {
          int tl = i * 16 + quad * 4 + reg;
          float sn, cs;
          __sincosf((float)(t0 + tl) * inv_ts, &sn, &cs);
          float v0 = (acc[i][0][reg] + bb[0]) * scale;
          float v1 = (acc[i][1][reg] + bb[1]) * scale;
          float v2 = (acc[i][2][reg] + bb[2]) * scale;
          float v3 = (acc[i][3][reg] + bb[3]) * scale;
          sb[tl * 72 + l15]      = f2bf(v0 * cs - v2 * sn);
          sb[tl * 72 + 16 + l15] = f2bf(v1);
          sb[tl * 72 + 32 + l15] = f2bf(v2 * cs + v0 * sn);
          sb[tl * 72 + 48 + l15] = f2bf(v3);
        }
      }
      __syncthreads();
      bf16_t* outp = (region == 0) ? p.outB0 : p.outB1;
      bf16_t* ob = outp + (((size_t)(b * 12 + h) * 2048 + t0) << 6);
#pragma unroll
      for (int pp = 0; pp < 8; pp++) {
        int row = pp * 8 + (lane >> 3), ch = (lane & 7) << 3;
        *(bf16x8*)(ob + row * 64 + ch) = *(const bf16x8*)&sb[row * 72 + ch];
      }
    } else {
#pragma unroll
      for (int i = 0; i < 4; i++)
#pragma unroll
        for (int j = 0; j < 4; j++)
#pragma unroll
          for (int reg = 0; reg < 4; reg++)
            sb[(j * 16 + l15) * 72 + i * 16 + quad * 4 + reg] =
                f2bf(acc[i][j][reg] + bb[j]);
      __syncthreads();
      bf16_t* ob = p.outB2 + (((size_t)(b * 12 + h)) << 17) + t0;
#pragma unroll
      for (int pp = 0; pp < 8; pp++) {
        int d = pp * 8 + (lane >> 3), ch = (lane & 7) << 3;
        *(bf16x8*)(ob + (size_t)d * 2048 + ch) = *(const bf16x8*)&sb[d * 72 + ch];
      }
    }
  } else {  // mode 2: FFN1 + exact GELU -> bf16
    bf16_t* sb = (bf16_t*)scr;  // [64][72]
    float bb[4];
#pragma unroll
    for (int j = 0; j < 4; j++) bb[j] = p.bias0[n0 + wn + j * 16 + l15];
#pragma unroll
    for (int i = 0; i < 4; i++)
#pragma unroll
      for (int j = 0; j < 4; j++)
#pragma unroll
        for (int reg = 0; reg < 4; reg++) {
          int tl = i * 16 + quad * 4 + reg;
          float x = acc[i][j][reg] + bb[j];
          float gv = 0.5f * x * (1.0f + erff(x * 0.70710678118654752f));
          sb[tl * 72 + j * 16 + l15] = f2bf(gv);
        }
    __syncthreads();
#pragma unroll
    for (int pp = 0; pp < 8; pp++) {
      int row = pp * 8 + (lane >> 3), ch = (lane & 7) << 3;
      *(bf16x8*)(p.outB0 + (size_t)(m0 + wm + row) * p.N + n0 + wn + ch) =
          *(const bf16x8*)&sb[row * 72 + ch];
    }
  }
}

// ---------------------------------------------------------------------------
// 64x64-tile GEMM for N=768 layers (WO, FFN2): fp32 out = acc + bias + resid.
// Single-buffer BK=128: 16 MFMA per barrier pair. 32 KiB LDS. 768 blocks.
// 128-col rows, XOR swizzle on 16B chunks: cc' = cc ^ (r&7).
// ---------------------------------------------------------------------------
__global__ __launch_bounds__(256, 4) void k_gemm64(
    const bf16_t* __restrict__ A, const bf16_t* __restrict__ Bt, int N, int K,
    const float* __restrict__ bias, const float* __restrict__ resid,
    float* __restrict__ outF) {
  __shared__ bf16_t lds[16384];  // 32 KiB: lA@0[8192], lB@8192[8192]
  const int tid = threadIdx.x;
  const int lane = tid & 63, wave = tid >> 6;
  const int quad = lane >> 4, l15 = lane & 15;
  const int wm = (wave >> 1) * 32, wn = (wave & 1) * 32;
  const int m0 = blockIdx.y * 64, n0 = blockIdx.x * 64;

  // staging: 64 rows x 16 chunks per tensor = 1024 slots; 4/thread/tensor.
  const char* gA[4];
  const char* gB[4];
#pragma unroll
  for (int pp = 0; pp < 4; pp++) {
    int slot = wave * 256 + pp * 64 + lane;
    int r = slot >> 4;
    int c = ((slot & 15) ^ (r & 7)) << 3;  // elems
    gA[pp] = (const char*)(A + (size_t)(m0 + r) * K + c);
    gB[pp] = (const char*)(Bt + (size_t)(n0 + r) * K + c);
  }

  const floatx4 z4 = {0.f, 0.f, 0.f, 0.f};
  floatx4 acc[2][2];
#pragma unroll
  for (int i = 0; i < 2; i++)
#pragma unroll
    for (int j = 0; j < 2; j++) acc[i][j] = z4;

  const int KT = K >> 7;
  bf16_t* Ad = lds + wave * 2048;
  bf16_t* Bd = lds + 8192 + wave * 2048;

  for (int kt = 0; kt < KT; kt++) {
    const size_t kb = (size_t)kt * 256;  // bytes (128 elems)
#pragma unroll
    for (int pp = 0; pp < 4; pp++) {
      g2l16(gA[pp] + kb, Ad + pp * 512);
      g2l16(gB[pp] + kb, Bd + pp * 512);
    }
    __syncthreads();
#pragma unroll
    for (int ks = 0; ks < 4; ks++) {
      bf16x8 af[2], bfr[2];
#pragma unroll
      for (int i = 0; i < 2; i++) {
        int ra = wm + i * 16 + l15;
        af[i] = *(const bf16x8*)(lds + ra * 128 +
                                 (((ks * 4 + quad) ^ (ra & 7)) << 3));
        int rb = wn + i * 16 + l15;
        bfr[i] = *(const bf16x8*)(lds + 8192 + rb * 128 +
                                  (((ks * 4 + quad) ^ (rb & 7)) << 3));
      }
#pragma unroll
      for (int i = 0; i < 2; i++)
#pragma unroll
        for (int j = 0; j < 2; j++) acc[i][j] = MFMA(af[i], bfr[j], acc[i][j]);
    }
    __syncthreads();
  }

  // epilogue: per-wave fp32 [32][32] scratch -> coalesced float4 stores
  float* s4 = (float*)lds + wave * 1024;
#pragma unroll
  for (int i = 0; i < 2; i++)
#pragma unroll
    for (int j = 0; j < 2; j++)
#pragma unroll
      for (int reg = 0; reg < 4; reg++)
        s4[(i * 16 + quad * 4 + reg) * 32 + j * 16 + l15] = acc[i][j][reg];
  __syncthreads();
#pragma unroll
  for (int pp = 0; pp < 4; pp++) {
    int row = pp * 8 + (lane >> 3);
    int c4 = (lane & 7) * 4;
    floatx4 v = *(const floatx4*)&s4[row * 32 + c4];
    size_t goff = (size_t)(m0 + wm + row) * N + n0 + wn + c4;
    floatx4 rv = *(const floatx4*)(resid + goff);
    floatx4 bv = *(const floatx4*)(bias + n0 + wn + c4);
    *(floatx4*)(outF + goff) = v + rv + bv;
  }
}

// ---------------------------------------------------------------------------
// Flash attention, exp2-domain, no max subtraction, variate bias added
// (tile-uniform) to the exp2 argument. Async dbuf, 1 barrier/iter, kv=64.
// ---------------------------------------------------------------------------
__global__ __launch_bounds__(256, 3) void k_flash(
    const bf16_t* __restrict__ qh, const bf16_t* __restrict__ kh,
    const bf16_t* __restrict__ vt, const float* __restrict__ ab,
    bf16_t* __restrict__ attnA) {
  __shared__ bf16_t sm[20480];  // 40 KiB
  bf16_t* lK = sm;              // [2][4096]
  bf16_t* lV = sm + 8192;       // [2][4096]
  bf16_t* lP = sm + 16384;      // [4][1024] wave-private

  const int tid = threadIdx.x, lane = tid & 63, wave = tid >> 6;
  const int quad = lane >> 4, l15 = lane & 15;
  const int qtile = blockIdx.x, bh = blockIdx.y;
  const int h = bh % 12, bq = bh / 12;
  const int qr0 = qtile * 64 + wave * 16;

  const bf16_t* Qb = qh + (size_t)bh * 2048 * 64;
  const bf16_t* Kb = kh + (size_t)bh * 2048 * 64;
  const bf16_t* Vb = vt + (size_t)bh * 64 * 2048;

  const char* gK[2];
  const char* gV[2];
#pragma unroll
  for (int pp = 0; pp < 2; pp++) {
    int slot = wave * 128 + pp * 64 + lane;
    int r = slot >> 3;
    int c8 = ((slot & 7) ^ (r & 7)) << 3;
    gK[pp] = (const char*)(Kb + r * 64 + c8);
    gV[pp] = (const char*)(Vb + (size_t)r * 2048 + c8);
  }

  bf16x8 qf[2];
#pragma unroll
  for (int ks = 0; ks < 2; ks++)
    qf[ks] = *(const bf16x8*)(Qb + (size_t)(qr0 + l15) * 64 + ks * 32 + quad * 8);

  int offK[4];
#pragma unroll
  for (int t4 = 0; t4 < 4; t4++) {
    int sr = t4 * 16 + l15;
    offK[t4] = sr * 64 + ((quad * 8) ^ ((sr & 7) << 3));
  }
  const int offP = l15 * 64 + ((quad * 8) ^ ((l15 & 7) << 3));

  const floatx4 z4 = {0.f, 0.f, 0.f, 0.f};
  float l_all[4] = {0.f, 0.f, 0.f, 0.f};
  floatx4 oacc[4];
#pragma unroll
  for (int dt = 0; dt < 4; dt++) oacc[dt] = z4;

  const float bc_same = ab[h * 2] * LOG2E;
  const float bc_diff = ab[h * 2 + 1] * LOG2E;
  const int myv = qtile >> 1;

  {
    bf16_t* K0 = lK + wave * 1024;
    bf16_t* V0 = lV + wave * 1024;
#pragma unroll
    for (int pp = 0; pp < 2; pp++) {
      g2l16(gK[pp], K0 + pp * 512);
      g2l16(gV[pp], V0 + pp * 512);
    }
  }
  __syncthreads();

  for (int kv = 0; kv < 32; kv++) {
    const int cur = kv & 1;
    if (kv + 1 < 32) {
      bf16_t* K1 = lK + (cur ^ 1) * 4096 + wave * 1024;
      bf16_t* V1 = lV + (cur ^ 1) * 4096 + wave * 1024;
      const size_t kb = (size_t)(kv + 1) * 8192, vb = (size_t)(kv + 1) * 128;
#pragma unroll
      for (int pp = 0; pp < 2; pp++) {
        g2l16(gK[pp] + kb, K1 + pp * 512);
        g2l16(gV[pp] + vb, V1 + pp * 512);
      }
    }
    const bf16_t* K0 = lK + cur * 4096;
    const bf16_t* V0 = lV + cur * 4096;

    floatx4 sacc[4] = {z4, z4, z4, z4};
#pragma unroll
    for (int ks = 0; ks < 2; ks++)
#pragma unroll
      for (int ct = 0; ct < 4; ct++)
        sacc[ct] = MFMA(qf[ks], *(const bf16x8*)(K0 + (offK[ct] ^ (ks * 32))),
                        sacc[ct]);

    // P = exp2(s' + bc), bc tile-uniform; row sums deferred to kernel end
    const float bc = ((kv >> 1) == myv) ? bc_same : bc_diff;
#pragma unroll
    for (int ct = 0; ct < 4; ct++)
#pragma unroll
      for (int reg = 0; reg < 4; reg++) {
        float pv = exp2f(sacc[ct][reg] + bc);
        sacc[ct][reg] = pv;
        l_all[reg] += pv;
      }

    bf16_t* myP = lP + wave * 1024;
#pragma unroll
    for (int ct = 0; ct < 4; ct++)
#pragma unroll
      for (int reg = 0; reg < 4; reg++) {
        int r = quad * 4 + reg, s = ct * 16 + l15;
        myP[r * 64 + (((s >> 3) ^ (r & 7)) << 3) + (s & 7)] =
            f2bf(sacc[ct][reg]);
      }
    lds_fence();

#pragma unroll
    for (int ks = 0; ks < 2; ks++) {
      bf16x8 pf = *(const bf16x8*)(myP + (offP ^ (ks * 32)));
#pragma unroll
      for (int dt = 0; dt < 4; dt++)
        oacc[dt] = MFMA(pf, *(const bf16x8*)(V0 + (offK[dt] ^ (ks * 32))),
                        oacc[dt]);
    }
    __syncthreads();
  }

  // final: cross-lane reduce l, normalize, store
  float inv_l[4];
#pragma unroll
  for (int reg = 0; reg < 4; reg++) {
    float la = l_all[reg];
    la += __shfl_xor(la, 1); la += __shfl_xor(la, 2);
    la += __shfl_xor(la, 4); la += __shfl_xor(la, 8);
    inv_l[reg] = 1.0f / la;
  }

  bf16_t* myP = lP + wave * 1024;
#pragma unroll
  for (int dt = 0; dt < 4; dt++)
#pragma unroll
    for (int reg = 0; reg < 4; reg++)
      myP[(quad * 4 + reg) * 64 + dt * 16 + l15] =
          f2bf(oacc[dt][reg] * inv_l[reg]);
  __syncthreads();
#pragma unroll
  for (int pp = 0; pp < 2; pp++) {
    int row = pp * 8 + (lane >> 3), ch = (lane & 7) << 3;
    *(bf16x8*)(attnA + ((size_t)(bq * 2048 + qr0 + row)) * 768 + h * 64 + ch) =
        *(const bf16x8*)&myP[row * 64 + ch];
  }
}

// ---------------------------------------------------------------------------
extern "C" void kernel_launch(void* const* d_in, const int* in_sizes, int n_in,
                              void* d_out, int out_size, void* d_ws,
                              size_t ws_size, hipStream_t stream) {
  const float* hs  = (const float*)d_in[0];
  const float* wq  = (const float*)d_in[1];
  const float* bq  = (const float*)d_in[2];
  const float* wk  = (const float*)d_in[3];
  const float* bk  = (const float*)d_in[4];
  const float* wv  = (const float*)d_in[5];
  const float* bv  = (const float*)d_in[6];
  const float* wo  = (const float*)d_in[7];
  const float* bo  = (const float*)d_in[8];
  const float* ab  = (const float*)d_in[9];
  const float* g1  = (const float*)d_in[10];
  const float* be1 = (const float*)d_in[11];
  const float* g3  = (const float*)d_in[12];
  const float* be3 = (const float*)d_in[13];
  const float* w1  = (const float*)d_in[14];
  const float* b1  = (const float*)d_in[15];
  const float* w2  = (const float*)d_in[16];
  const float* b2  = (const float*)d_in[17];

  char* ws = (char*)d_ws;
  size_t off = 0;
  auto alloc = [&](size_t bytes) -> void* {
    void* p = ws + off;
    off += (bytes + 255) & ~(size_t)255;
    return p;
  };
  bf16_t* wqkvT = (bf16_t*)alloc((size_t)2304 * 768 * 2);
  bf16_t* woT   = (bf16_t*)alloc((size_t)768 * 768 * 2);
  bf16_t* w1T   = (bf16_t*)alloc((size_t)3072 * 768 * 2);
  bf16_t* w2T   = (bf16_t*)alloc((size_t)768 * 3072 * 2);
  bf16_t* ni    = (bf16_t*)alloc((size_t)4096 * 768 * 2);
  bf16_t* qhB   = (bf16_t*)alloc((size_t)24 * 2048 * 64 * 2);
  bf16_t* khB   = (bf16_t*)alloc((size_t)24 * 2048 * 64 * 2);
  bf16_t* vtB   = (bf16_t*)alloc((size_t)24 * 64 * 2048 * 2);
  bf16_t* attnA = (bf16_t*)alloc((size_t)4096 * 768 * 2);
  float*  resid1 = (float*)alloc((size_t)4096 * 768 * 4);
  bf16_t* ffn1o = qhB;  // overlay: q/k/v/attn region dead by FFN1 time

  // prep: all transposes + LN1, one dispatch
  PrepP pp = {wq, wk, wv, wo, w1, w2, wqkvT, woT, w1T, w2T, hs, g1, be1, ni};
  k_prep<<<11008, 256, 0, stream>>>(pp);

  // QKV (fused, N=2304): bias, q*0.125*log2e, p-RoPE, head-layout scatter
  GemmP gqkv = {ni, wqkvT, 4096, 2304, 768, 0,
                bq, bk, bv, nullptr, qhB, khB, vtB};
  k_gemm<<<dim3(18, 32), 256, 0, stream>>>(gqkv);

  // flash attention (exp2 domain)
  k_flash<<<dim3(32, 24), 256, 0, stream>>>(qhB, khB, vtB, ab, attnA);

  // attn @ wo + bo + residual(hidden) -> resid1 (fp32)
  k_gemm64<<<dim3(12, 64), 256, 0, stream>>>(attnA, woT, 768, 768, bo, hs,
                                             resid1);

  // LN3
  k_layernorm<<<4096, 256, 0, stream>>>(resid1, g3, be3, ni);

  // FFN1 + exact GELU -> bf16
  GemmP gf1 = {ni, w1T, 4096, 3072, 768, 2,
               b1, nullptr, nullptr, nullptr, ffn1o, nullptr, nullptr};
  k_gemm<<<dim3(24, 32), 256, 0, stream>>>(gf1);

  // FFN2 + b2 + residual -> d_out (fp32 [4096][768])
  k_gemm64<<<dim3(12, 64), 256, 0, stream>>>(ffn1o, w2T, 768, 3072, b2,
                                             resid1, (float*)d_out);
}